// Round 2
// baseline (6185.421 us; speedup 1.0000x reference)
//
#include <hip/hip_runtime.h>

typedef float f32x4 __attribute__((ext_vector_type(4)));
typedef _Float16 f16x8 __attribute__((ext_vector_type(8)));

#define NN 50000
#define EE 800000
#define GD 512
#define H1C 128
#define RR 8
#define NC1 1152   // 8*128 rel + 128 root
#define NC2 512    // q|k|v|skip

// ---------- helpers ----------
__device__ __forceinline__ unsigned short f2h(float f){
  _Float16 h = (_Float16)f;            // RNE via v_cvt_f16_f32
  unsigned short u; __builtin_memcpy(&u, &h, 2); return u;
}
__device__ __forceinline__ float h2f(unsigned short u){
  _Float16 h; __builtin_memcpy(&h, &u, 2); return (float)h;
}
__device__ __forceinline__ void unpack8h(uint4 v, float* f){
  const unsigned short* p = (const unsigned short*)&v;
  #pragma unroll
  for (int i = 0; i < 8; i++) f[i] = h2f(p[i]);
}
__device__ __forceinline__ void atomicMaxF(float* addr, float val){
  if (val >= 0.0f) atomicMax((int*)addr, __float_as_int(val));
  else             atomicMin((unsigned int*)addr, __float_as_uint(val));
}

// ---------- small utility kernels ----------
__global__ void k_fill(float* p, float v, int n){
  int i = blockIdx.x * blockDim.x + threadIdx.x;
  if (i < n) p[i] = v;
}

__global__ void k_cast_f16(const float* __restrict__ in, unsigned short* __restrict__ out, int n){
  int i = (blockIdx.x * blockDim.x + threadIdx.x) * 4;
  if (i + 3 < n){
    float4 v = *(const float4*)(in + i);
    ushort4 o;
    o.x = f2h(v.x); o.y = f2h(v.y); o.z = f2h(v.z); o.w = f2h(v.w);
    *(ushort4*)(out + i) = o;
  }
}

// WcatT[j][f], j in [0,1152): j<1024 -> W_rel[j>>7][f][j&127]; else W_root[f][j-1024]
__global__ void k_pack_w1(const float* __restrict__ W_rel, const float* __restrict__ W_root,
                          unsigned short* __restrict__ wcatT){
  int idx = blockIdx.x * blockDim.x + threadIdx.x;
  if (idx >= NC1 * GD) return;
  int j = idx >> 9;      // / 512
  int f = idx & 511;
  float v;
  if (j < 1024) v = W_rel[((size_t)(j >> 7) * GD + f) * H1C + (j & 127)];
  else          v = W_root[(size_t)f * H1C + (j - 1024)];
  wcatT[(size_t)j * GD + f] = f2h(v);
}

// W2catT[j][f], j in [0,512): block m=j>>7 selects Wq/Wk/Wv/Wskip; also bias2
__global__ void k_pack_w2(const float* __restrict__ Wq, const float* __restrict__ Wk,
                          const float* __restrict__ Wv, const float* __restrict__ Ws,
                          const float* __restrict__ bq, const float* __restrict__ bk,
                          const float* __restrict__ bv, const float* __restrict__ bs,
                          unsigned short* __restrict__ w2T, float* __restrict__ bias2){
  int idx = blockIdx.x * blockDim.x + threadIdx.x;
  if (idx >= NC2 * H1C) return;
  int j = idx >> 7;      // / 128
  int f = idx & 127;
  int m = j >> 7;
  int hc = j & 127;
  const float* W = (m == 0) ? Wq : (m == 1) ? Wk : (m == 2) ? Wv : Ws;
  w2T[(size_t)j * H1C + f] = f2h(W[(size_t)f * H1C + hc]);
  if (f == 0){
    const float* B = (m == 0) ? bq : (m == 1) ? bk : (m == 2) ? bv : bs;
    bias2[j] = B[hc];
  }
}

// ---------- MFMA GEMM: C[M][Nout] = A[M][K] @ Bt[Nout][K]^T (+bias), fp16 in/out ----------
#define TILE 128
#define BK 64
#define LDSS 72   // 64 + 8 pad (f16 elems)

__global__ __launch_bounds__(256) void k_gemm(
    const unsigned short* __restrict__ A,
    const unsigned short* __restrict__ Bt,
    unsigned short* __restrict__ C,
    const float* __restrict__ bias,
    int M, int Nout, int K)
{
  __shared__ unsigned short As[TILE][LDSS];
  __shared__ unsigned short Bs[TILE][LDSS];
  int tid = threadIdx.x;
  int row0 = blockIdx.x * TILE;
  int col0 = blockIdx.y * TILE;
  int wave = tid >> 6, lane = tid & 63;
  int wm = (wave >> 1) * 64, wn = (wave & 1) * 64;
  int l16 = lane & 15, quad = lane >> 4;

  f32x4 acc[4][4] = {};

  for (int k0 = 0; k0 < K; k0 += BK){
    __syncthreads();
    #pragma unroll
    for (int i = 0; i < 4; i++){
      int c = tid + i * 256;
      int r = c >> 3, col8 = (c & 7) * 8;
      int gr = row0 + r; if (gr >= M) gr = M - 1;     // clamp; stores guarded
      *(f16x8*)&As[r][col8] = *(const f16x8*)(A + (size_t)gr * K + k0 + col8);
    }
    #pragma unroll
    for (int i = 0; i < 4; i++){
      int c = tid + i * 256;
      int r = c >> 3, col8 = (c & 7) * 8;
      int gc = col0 + r;                               // Nout divisible by 128 here
      *(f16x8*)&Bs[r][col8] = *(const f16x8*)(Bt + (size_t)gc * K + k0 + col8);
    }
    __syncthreads();
    #pragma unroll
    for (int ks = 0; ks < BK; ks += 32){
      f16x8 af[4], bfr[4];
      #pragma unroll
      for (int i = 0; i < 4; i++) af[i] = *(const f16x8*)&As[wm + i*16 + l16][ks + quad*8];
      #pragma unroll
      for (int j = 0; j < 4; j++) bfr[j] = *(const f16x8*)&Bs[wn + j*16 + l16][ks + quad*8];
      #pragma unroll
      for (int i = 0; i < 4; i++)
        #pragma unroll
        for (int j = 0; j < 4; j++)
          acc[i][j] = __builtin_amdgcn_mfma_f32_16x16x32_f16(af[i], bfr[j], acc[i][j], 0, 0, 0);
    }
  }

  // epilogue: C/D layout col=lane&15, row=quad*4+reg
  #pragma unroll
  for (int i = 0; i < 4; i++){
    int rbase = row0 + wm + i*16 + quad*4;
    #pragma unroll
    for (int j = 0; j < 4; j++){
      int col = col0 + wn + j*16 + l16;
      float b = bias ? bias[col] : 0.0f;
      #pragma unroll
      for (int rr = 0; rr < 4; rr++){
        int row = rbase + rr;
        if (row < M) C[(size_t)row * Nout + col] = f2h(acc[i][j][rr] + b);
      }
    }
  }
}

// ---------- RGCN edge kernels ----------
__global__ void k_count(const int* __restrict__ ei, const int* __restrict__ et,
                        float* __restrict__ cnt, int E){
  int e = blockIdx.x * blockDim.x + threadIdx.x;
  if (e < E) atomicAdd(&cnt[(size_t)ei[E + e] * RR + et[e]], 1.0f);
}

// h[n][c] = xW_root + b1
__global__ void k_init_h(const unsigned short* __restrict__ xW, const float* __restrict__ b1,
                         float* __restrict__ h, int n){
  int idx = blockIdx.x * blockDim.x + threadIdx.x;
  if (idx >= n) return;
  int node = idx >> 7, c = idx & 127;
  h[idx] = h2f(xW[(size_t)node * NC1 + 1024 + c]) + b1[c];
}

// h[dst] += xW[src, etype] / denom   (16 lanes/edge, 8 ch/lane)
__global__ void k_scatter_msg(const int* __restrict__ ei, const int* __restrict__ et,
                              const unsigned short* __restrict__ xW,
                              const float* __restrict__ cnt, float* __restrict__ h, int E){
  int t = blockIdx.x * blockDim.x + threadIdx.x;
  int e = t >> 4, j = t & 15;
  if (e >= E) return;
  int src = ei[e], dst = ei[E + e], r = et[e];
  float inv = 1.0f / fmaxf(cnt[(size_t)dst * RR + r], 1.0f);
  uint4 u = *(const uint4*)(xW + (size_t)src * NC1 + r * H1C + j * 8);
  float f[8]; unpack8h(u, f);
  float* hd = h + (size_t)dst * H1C + j * 8;
  #pragma unroll
  for (int i = 0; i < 8; i++) atomicAdd(&hd[i], f[i] * inv);
}

// ---------- attention edge kernels ----------
__global__ void k_score(const int* __restrict__ ei, const unsigned short* __restrict__ qkvs,
                        float* __restrict__ score, float* __restrict__ smax, int E){
  int t = blockIdx.x * blockDim.x + threadIdx.x;
  int e = t >> 4, j = t & 15;
  if (e >= E) return;
  int src = ei[e], dst = ei[E + e];
  uint4 qa = *(const uint4*)(qkvs + (size_t)dst * NC2 + j * 8);          // q
  uint4 ka = *(const uint4*)(qkvs + (size_t)src * NC2 + 128 + j * 8);    // k
  float qf[8], kf[8]; unpack8h(qa, qf); unpack8h(ka, kf);
  float s = 0.0f;
  #pragma unroll
  for (int i = 0; i < 8; i++) s += qf[i] * kf[i];
  #pragma unroll
  for (int off = 8; off >= 1; off >>= 1) s += __shfl_xor(s, off, 16);
  if (j == 0){
    s *= 0.08838834764831845f;   // 1/sqrt(128)
    score[e] = s;
    atomicMaxF(&smax[dst], s);
  }
}

__global__ void k_expsum(const int* __restrict__ ei, float* __restrict__ score,
                         const float* __restrict__ smax, float* __restrict__ ssum, int E){
  int e = blockIdx.x * blockDim.x + threadIdx.x;
  if (e >= E) return;
  int dst = ei[E + e];
  float ex = expf(score[e] - smax[dst]);
  score[e] = ex;
  atomicAdd(&ssum[dst], ex);
}

__global__ void k_init_h2(const unsigned short* __restrict__ qkvs, float* __restrict__ h2, int n){
  int idx = blockIdx.x * blockDim.x + threadIdx.x;
  if (idx >= n) return;
  int node = idx >> 7, c = idx & 127;
  h2[idx] = h2f(qkvs[(size_t)node * NC2 + 384 + c]);   // skip path (bias already added)
}

__global__ void k_scatter_attn(const int* __restrict__ ei, const unsigned short* __restrict__ qkvs,
                               const float* __restrict__ ex, const float* __restrict__ ssum,
                               float* __restrict__ h2, int E){
  int t = blockIdx.x * blockDim.x + threadIdx.x;
  int e = t >> 4, j = t & 15;
  if (e >= E) return;
  int src = ei[e], dst = ei[E + e];
  float a = ex[e] / fmaxf(ssum[dst], 1e-16f);
  uint4 u = *(const uint4*)(qkvs + (size_t)src * NC2 + 256 + j * 8);    // v
  float f[8]; unpack8h(u, f);
  float* hd = h2 + (size_t)dst * H1C + j * 8;
  #pragma unroll
  for (int i = 0; i < 8; i++) atomicAdd(&hd[i], a * f[i]);
}

// ---------- batchnorm + activation ----------
__global__ __launch_bounds__(256) void k_bn_reduce(const float* __restrict__ h2,
                                                   float* __restrict__ bn, int Nrows){
  __shared__ float ls[256], lq[256];
  int c = threadIdx.x & 127;
  int half = threadIdx.x >> 7;
  float s = 0.0f, q = 0.0f;
  for (int r = blockIdx.x * 2 + half; r < Nrows; r += gridDim.x * 2){
    float v = h2[(size_t)r * H1C + c];
    s += v; q += v * v;
  }
  ls[threadIdx.x] = s; lq[threadIdx.x] = q;
  __syncthreads();
  if (half == 0){
    atomicAdd(&bn[c],        ls[c] + ls[c + 128]);
    atomicAdd(&bn[128 + c],  lq[c] + lq[c + 128]);
  }
}

__global__ void k_bn_final(float* __restrict__ bn, int Nrows){
  int c = threadIdx.x;
  if (c >= 128) return;
  float mu = bn[c] / (float)Nrows;
  float var = bn[128 + c] / (float)Nrows - mu * mu;
  bn[256 + c] = mu;
  bn[384 + c] = rsqrtf(var + 1e-5f);
}

__global__ void k_out(const float* __restrict__ h2, const float* __restrict__ bn,
                      const float* __restrict__ gamma, const float* __restrict__ beta,
                      float* __restrict__ out, int n){
  int idx = blockIdx.x * blockDim.x + threadIdx.x;
  if (idx >= n) return;
  int c = idx & 127;
  float v = (h2[idx] - bn[256 + c]) * bn[384 + c];
  float o = gamma[c] * v + beta[c];
  out[idx] = (o >= 0.0f) ? o : 0.01f * o;
}

// ---------- launcher ----------
extern "C" void kernel_launch(void* const* d_in, const int* in_sizes, int n_in,
                              void* d_out, int out_size, void* d_ws, size_t ws_size,
                              hipStream_t stream) {
  const float* x      = (const float*)d_in[0];
  const int*   ei     = (const int*)d_in[1];
  const int*   et     = (const int*)d_in[2];
  const float* W_rel  = (const float*)d_in[3];
  const float* W_root = (const float*)d_in[4];
  const float* b1     = (const float*)d_in[5];
  const float* Wq     = (const float*)d_in[6];
  const float* bq     = (const float*)d_in[7];
  const float* Wk     = (const float*)d_in[8];
  const float* bk     = (const float*)d_in[9];
  const float* Wv     = (const float*)d_in[10];
  const float* bv     = (const float*)d_in[11];
  const float* Wskip  = (const float*)d_in[12];
  const float* bskip  = (const float*)d_in[13];
  const float* gamma  = (const float*)d_in[14];
  const float* beta   = (const float*)d_in[15];
  float* out = (float*)d_out;

  const int N = NN, E = EE;
  char* ws = (char*)d_ws;
  size_t off = 0;
  auto alloc = [&](size_t bytes){ size_t r = off; off = (off + bytes + 255) & ~(size_t)255; return r; };

  size_t o_x16   = alloc((size_t)N * GD * 2);     // x fp16; REUSED as qkvs (same size) after gemm1
  size_t o_w1    = alloc((size_t)NC1 * GD * 2);   // WcatT fp16
  size_t o_xw    = alloc((size_t)N * NC1 * 2);    // xW fp16; REUSED as h2 (f32, smaller) later
  size_t o_cnt   = alloc((size_t)N * RR * 4);
  size_t o_h     = alloc((size_t)N * H1C * 4);
  size_t o_h16   = alloc((size_t)N * H1C * 2);
  size_t o_w2    = alloc((size_t)NC2 * H1C * 2);
  size_t o_b2    = alloc((size_t)NC2 * 4);
  size_t o_score = alloc((size_t)E * 4);
  size_t o_smax  = alloc((size_t)N * 4);
  size_t o_ssum  = alloc((size_t)N * 4);
  size_t o_bn    = alloc((size_t)512 * 4);

  unsigned short* x16   = (unsigned short*)(ws + o_x16);
  unsigned short* qkvs  = (unsigned short*)(ws + o_x16);   // reuse
  unsigned short* wcatT = (unsigned short*)(ws + o_w1);
  unsigned short* xW    = (unsigned short*)(ws + o_xw);
  float*          h2    = (float*)(ws + o_xw);             // reuse
  float*          cnt   = (float*)(ws + o_cnt);
  float*          h     = (float*)(ws + o_h);
  unsigned short* h16   = (unsigned short*)(ws + o_h16);
  unsigned short* w2T   = (unsigned short*)(ws + o_w2);
  float*          bias2 = (float*)(ws + o_b2);
  float*          score = (float*)(ws + o_score);
  float*          smax  = (float*)(ws + o_smax);
  float*          ssum  = (float*)(ws + o_ssum);
  float*          bn    = (float*)(ws + o_bn);

  const int TPB = 256;

  // 1. counts
  k_fill<<<(N * RR + TPB - 1) / TPB, TPB, 0, stream>>>(cnt, 0.0f, N * RR);
  k_count<<<(E + TPB - 1) / TPB, TPB, 0, stream>>>(ei, et, cnt, E);

  // 2. cast x, pack W1, GEMM1: xW = x @ [W_rel | W_root]
  k_cast_f16<<<((size_t)N * GD / 4 + TPB - 1) / TPB, TPB, 0, stream>>>(x, x16, N * GD);
  k_pack_w1<<<(NC1 * GD + TPB - 1) / TPB, TPB, 0, stream>>>(W_rel, W_root, wcatT);
  {
    dim3 grid((N + TILE - 1) / TILE, NC1 / TILE);
    k_gemm<<<grid, TPB, 0, stream>>>(x16, wcatT, xW, nullptr, N, NC1, GD);
  }

  // 3. h = root + b1 + mean-aggregated messages
  k_init_h<<<((size_t)N * H1C + TPB - 1) / TPB, TPB, 0, stream>>>(xW, b1, h, N * H1C);
  k_scatter_msg<<<((size_t)E * 16 + TPB - 1) / TPB, TPB, 0, stream>>>(ei, et, xW, cnt, h, E);

  // 4. GEMM2: qkvs = h @ [Wq|Wk|Wv|Wskip] + biases
  k_cast_f16<<<((size_t)N * H1C / 4 + TPB - 1) / TPB, TPB, 0, stream>>>(h, h16, N * H1C);
  k_pack_w2<<<(NC2 * H1C + TPB - 1) / TPB, TPB, 0, stream>>>(Wq, Wk, Wv, Wskip, bq, bk, bv, bskip, w2T, bias2);
  {
    dim3 grid((N + TILE - 1) / TILE, NC2 / TILE);
    k_gemm<<<grid, TPB, 0, stream>>>(h16, w2T, qkvs, bias2, N, NC2, H1C);
  }

  // 5. attention
  k_fill<<<(N + TPB - 1) / TPB, TPB, 0, stream>>>(smax, -INFINITY, N);
  k_fill<<<(N + TPB - 1) / TPB, TPB, 0, stream>>>(ssum, 0.0f, N);
  k_score<<<((size_t)E * 16 + TPB - 1) / TPB, TPB, 0, stream>>>(ei, qkvs, score, smax, E);
  k_expsum<<<(E + TPB - 1) / TPB, TPB, 0, stream>>>(ei, score, smax, ssum, E);
  k_init_h2<<<((size_t)N * H1C + TPB - 1) / TPB, TPB, 0, stream>>>(qkvs, h2, N * H1C);
  k_scatter_attn<<<((size_t)E * 16 + TPB - 1) / TPB, TPB, 0, stream>>>(ei, qkvs, score, ssum, h2, E);

  // 6. batchnorm + leaky relu
  k_fill<<<1, 512, 0, stream>>>(bn, 0.0f, 512);
  k_bn_reduce<<<256, TPB, 0, stream>>>(h2, bn, N);
  k_bn_final<<<1, 128, 0, stream>>>(bn, N);
  k_out<<<((size_t)N * H1C + TPB - 1) / TPB, TPB, 0, stream>>>(h2, bn, gamma, beta, out, N * H1C);
}

// Round 3
// 752.281 us; speedup vs baseline: 8.2222x; 8.2222x over previous
//
#include <hip/hip_runtime.h>

typedef float f32x4 __attribute__((ext_vector_type(4)));
typedef _Float16 f16x8 __attribute__((ext_vector_type(8)));

#define NN 50000
#define EE 800000
#define GD 512
#define H1C 128
#define RR 8
#define NC1 1152   // 8*128 rel + 128 root
#define NC2 512    // q|k|v|skip
#define SCAN_BLK 256

// ---------- helpers ----------
__device__ __forceinline__ unsigned short f2h(float f){
  _Float16 h = (_Float16)f;
  unsigned short u; __builtin_memcpy(&u, &h, 2); return u;
}
__device__ __forceinline__ float h2f(unsigned short u){
  _Float16 h; __builtin_memcpy(&h, &u, 2); return (float)h;
}
__device__ __forceinline__ float2 h2f2(unsigned v){
  return make_float2(h2f((unsigned short)(v & 0xFFFFu)), h2f((unsigned short)(v >> 16)));
}
__device__ __forceinline__ float wredsum(float v){
  #pragma unroll
  for (int off = 32; off >= 1; off >>= 1) v += __shfl_xor(v, off, 64);
  return v;
}
__device__ __forceinline__ float wredmax(float v){
  #pragma unroll
  for (int off = 32; off >= 1; off >>= 1) v = fmaxf(v, __shfl_xor(v, off, 64));
  return v;
}

// ---------- utility kernels ----------
__global__ void k_fill_u32(unsigned* p, unsigned v, int n){
  int i = blockIdx.x * blockDim.x + threadIdx.x;
  if (i < n) p[i] = v;
}

__global__ void k_cast_f16(const float* __restrict__ in, unsigned short* __restrict__ out, int n){
  int i = (blockIdx.x * blockDim.x + threadIdx.x) * 4;
  if (i + 3 < n){
    float4 v = *(const float4*)(in + i);
    ushort4 o;
    o.x = f2h(v.x); o.y = f2h(v.y); o.z = f2h(v.z); o.w = f2h(v.w);
    *(ushort4*)(out + i) = o;
  }
}

__global__ void k_pack_w1(const float* __restrict__ W_rel, const float* __restrict__ W_root,
                          unsigned short* __restrict__ wcatT){
  int idx = blockIdx.x * blockDim.x + threadIdx.x;
  if (idx >= NC1 * GD) return;
  int j = idx >> 9;
  int f = idx & 511;
  float v;
  if (j < 1024) v = W_rel[((size_t)(j >> 7) * GD + f) * H1C + (j & 127)];
  else          v = W_root[(size_t)f * H1C + (j - 1024)];
  wcatT[(size_t)j * GD + f] = f2h(v);
}

__global__ void k_pack_w2(const float* __restrict__ Wq, const float* __restrict__ Wk,
                          const float* __restrict__ Wv, const float* __restrict__ Ws,
                          const float* __restrict__ bq, const float* __restrict__ bk,
                          const float* __restrict__ bv, const float* __restrict__ bs,
                          unsigned short* __restrict__ w2T, float* __restrict__ bias2){
  int idx = blockIdx.x * blockDim.x + threadIdx.x;
  if (idx >= NC2 * H1C) return;
  int j = idx >> 7;
  int f = idx & 127;
  int m = j >> 7;
  int hc = j & 127;
  const float* W = (m == 0) ? Wq : (m == 1) ? Wk : (m == 2) ? Wv : Ws;
  w2T[(size_t)j * H1C + f] = f2h(W[(size_t)f * H1C + hc]);
  if (f == 0){
    const float* B = (m == 0) ? bq : (m == 1) ? bk : (m == 2) ? bv : bs;
    bias2[j] = B[hc];
  }
}

// ---------- counting sort by dst ----------
// deg[dst]++ (int), cnt[dst*8+rel] += 1.0f (float, for RGCN mean)
__global__ void k_hist(const int* __restrict__ ei, const int* __restrict__ et,
                       int* __restrict__ deg, float* __restrict__ cnt, int E){
  int e = blockIdx.x * blockDim.x + threadIdx.x;
  if (e >= E) return;
  int dst = ei[E + e];
  atomicAdd(&deg[dst], 1);
  atomicAdd(&cnt[(size_t)dst * RR + et[e]], 1.0f);
}

__global__ void k_scan_partial(const int* __restrict__ deg, int* __restrict__ bsum, int n){
  __shared__ int s[SCAN_BLK];
  int i = blockIdx.x * SCAN_BLK + threadIdx.x;
  s[threadIdx.x] = (i < n) ? deg[i] : 0;
  __syncthreads();
  for (int off = 128; off >= 1; off >>= 1){
    if (threadIdx.x < off) s[threadIdx.x] += s[threadIdx.x + off];
    __syncthreads();
  }
  if (threadIdx.x == 0) bsum[blockIdx.x] = s[0];
}

__global__ void k_scan_top(int* __restrict__ bsum, int* __restrict__ boff, int nb){
  __shared__ int s[SCAN_BLK];
  int t = threadIdx.x;
  int v = (t < nb) ? bsum[t] : 0;
  s[t] = v;
  __syncthreads();
  #pragma unroll
  for (int off = 1; off < SCAN_BLK; off <<= 1){
    int tv = (t >= off) ? s[t - off] : 0;
    __syncthreads();
    s[t] += tv;
    __syncthreads();
  }
  if (t < nb) boff[t] = s[t] - v;   // exclusive
}

__global__ void k_scan_final(const int* __restrict__ deg, const int* __restrict__ boff,
                             int* __restrict__ base, int n){
  __shared__ int s[SCAN_BLK];
  int i = blockIdx.x * SCAN_BLK + threadIdx.x;
  int t = threadIdx.x;
  int v = (i < n) ? deg[i] : 0;
  s[t] = v;
  __syncthreads();
  #pragma unroll
  for (int off = 1; off < SCAN_BLK; off <<= 1){
    int tv = (t >= off) ? s[t - off] : 0;
    __syncthreads();
    s[t] += tv;
    __syncthreads();
  }
  if (i < n) base[i] = s[t] - v + boff[blockIdx.x];   // exclusive global
}

// sortedSR[pos] = src | (rel<<16)
__global__ void k_scatter_perm(const int* __restrict__ ei, const int* __restrict__ et,
                               const int* __restrict__ base, int* __restrict__ cursor,
                               unsigned* __restrict__ sortedSR, int E){
  int e = blockIdx.x * blockDim.x + threadIdx.x;
  if (e >= E) return;
  int dst = ei[E + e];
  int pos = base[dst] + atomicAdd(&cursor[dst], 1);
  sortedSR[pos] = (unsigned)(ei[e] & 0xFFFF) | ((unsigned)et[e] << 16);
}

// ---------- MFMA GEMM: C[M][Nout] = A[M][K] @ Bt[Nout][K]^T (+bias), fp16 in/out ----------
#define TILE 128
#define BK 64
#define LDSS 72

__global__ __launch_bounds__(256) void k_gemm(
    const unsigned short* __restrict__ A,
    const unsigned short* __restrict__ Bt,
    unsigned short* __restrict__ C,
    const float* __restrict__ bias,
    int M, int Nout, int K)
{
  __shared__ unsigned short As[TILE][LDSS];
  __shared__ unsigned short Bs[TILE][LDSS];
  int tid = threadIdx.x;
  int row0 = blockIdx.x * TILE;
  int col0 = blockIdx.y * TILE;
  int wave = tid >> 6, lane = tid & 63;
  int wm = (wave >> 1) * 64, wn = (wave & 1) * 64;
  int l16 = lane & 15, quad = lane >> 4;

  f32x4 acc[4][4] = {};

  for (int k0 = 0; k0 < K; k0 += BK){
    __syncthreads();
    #pragma unroll
    for (int i = 0; i < 4; i++){
      int c = tid + i * 256;
      int r = c >> 3, col8 = (c & 7) * 8;
      int gr = row0 + r; if (gr >= M) gr = M - 1;
      *(f16x8*)&As[r][col8] = *(const f16x8*)(A + (size_t)gr * K + k0 + col8);
    }
    #pragma unroll
    for (int i = 0; i < 4; i++){
      int c = tid + i * 256;
      int r = c >> 3, col8 = (c & 7) * 8;
      int gc = col0 + r;
      *(f16x8*)&Bs[r][col8] = *(const f16x8*)(Bt + (size_t)gc * K + k0 + col8);
    }
    __syncthreads();
    #pragma unroll
    for (int ks = 0; ks < BK; ks += 32){
      f16x8 af[4], bfr[4];
      #pragma unroll
      for (int i = 0; i < 4; i++) af[i] = *(const f16x8*)&As[wm + i*16 + l16][ks + quad*8];
      #pragma unroll
      for (int j = 0; j < 4; j++) bfr[j] = *(const f16x8*)&Bs[wn + j*16 + l16][ks + quad*8];
      #pragma unroll
      for (int i = 0; i < 4; i++)
        #pragma unroll
        for (int j = 0; j < 4; j++)
          acc[i][j] = __builtin_amdgcn_mfma_f32_16x16x32_f16(af[i], bfr[j], acc[i][j], 0, 0, 0);
    }
  }

  #pragma unroll
  for (int i = 0; i < 4; i++){
    int rbase = row0 + wm + i*16 + quad*4;
    #pragma unroll
    for (int j = 0; j < 4; j++){
      int col = col0 + wn + j*16 + l16;
      float b = bias ? bias[col] : 0.0f;
      #pragma unroll
      for (int rr = 0; rr < 4; rr++){
        int row = rbase + rr;
        if (row < M) C[(size_t)row * Nout + col] = f2h(acc[i][j][rr] + b);
      }
    }
  }
}

// ---------- RGCN segmented reduce: wave per node ----------
// h16[v][c] = f16( xW[v][1024+c] + b1[c] + sum_e xW[src_e][rel_e*128+c] / cnt[v][rel_e] )
__global__ __launch_bounds__(256) void k_rgcn_seg(
    const int* __restrict__ base, const int* __restrict__ deg,
    const unsigned* __restrict__ sortedSR,
    const unsigned short* __restrict__ xW, const float* __restrict__ cnt,
    const float* __restrict__ b1, unsigned short* __restrict__ h16)
{
  int v = blockIdx.x * 4 + (threadIdx.x >> 6);
  if (v >= NN) return;
  int lane = threadIdx.x & 63;
  int start = base[v], d = deg[v];

  // root + bias
  float2 root = h2f2(*(const unsigned*)(xW + (size_t)v * NC1 + 1024 + 2 * lane));
  float o0 = root.x + b1[2 * lane];
  float o1 = root.y + b1[2 * lane + 1];

  const float* cv = cnt + (size_t)v * RR;

  for (int cb = 0; cb < d; cb += 64){
    int cc = min(64, d - cb);
    unsigned sr = (lane < cc) ? sortedSR[start + cb + lane] : 0u;
    for (int i = 0; i < cc; i++){
      unsigned sri = __shfl((int)sr, i, 64);
      int src = (int)(sri & 0xFFFFu);
      int rel = (int)(sri >> 16);
      float inv = 1.0f / fmaxf(cv[rel], 1.0f);
      float2 m = h2f2(*(const unsigned*)(xW + (size_t)src * NC1 + rel * H1C + 2 * lane));
      o0 += m.x * inv;
      o1 += m.y * inv;
    }
  }
  unsigned out = (unsigned)f2h(o0) | ((unsigned)f2h(o1) << 16);
  *(unsigned*)(h16 + (size_t)v * H1C + 2 * lane) = out;
}

// ---------- fused attention: wave per node, online softmax ----------
// h2[v][c] = skip[v][c] + (sum_e alpha_e * v[src_e][c])
__global__ __launch_bounds__(256) void k_attn_seg(
    const int* __restrict__ base, const int* __restrict__ deg,
    const unsigned* __restrict__ sortedSR,
    const unsigned short* __restrict__ qkvs, float* __restrict__ h2)
{
  int v = blockIdx.x * 4 + (threadIdx.x >> 6);
  if (v >= NN) return;
  int lane = threadIdx.x & 63;
  int start = base[v], d = deg[v];

  float2 q = h2f2(*(const unsigned*)(qkvs + (size_t)v * NC2 + 2 * lane));
  float o0 = 0.0f, o1 = 0.0f, m = -INFINITY, l = 0.0f;
  const float sc = 0.08838834764831845f;   // 1/sqrt(128)

  for (int cb = 0; cb < d; cb += 64){
    int cc = min(64, d - cb);
    unsigned sr = (lane < cc) ? sortedSR[start + cb + lane] : 0u;
    int mysrc = (int)(sr & 0xFFFFu);

    // scores for this chunk
    float s_my = -INFINITY;
    for (int i = 0; i < cc; i++){
      int src = __shfl(mysrc, i, 64);
      float2 k = h2f2(*(const unsigned*)(qkvs + (size_t)src * NC2 + 128 + 2 * lane));
      float p = q.x * k.x + q.y * k.y;
      p = wredsum(p);
      if (lane == i) s_my = p * sc;
    }

    // online softmax update
    float M = wredmax(s_my);
    float newm = fmaxf(m, M);
    float scale = expf(m - newm);     // 0 on first chunk (m=-inf)
    o0 *= scale; o1 *= scale; l *= scale;
    float e_my = (lane < cc) ? expf(s_my - newm) : 0.0f;
    l += wredsum(e_my);

    // alpha-weighted V accumulate
    for (int i = 0; i < cc; i++){
      float a = __shfl(e_my, i, 64);
      int src = __shfl(mysrc, i, 64);
      float2 vv = h2f2(*(const unsigned*)(qkvs + (size_t)src * NC2 + 256 + 2 * lane));
      o0 += a * vv.x;
      o1 += a * vv.y;
    }
    m = newm;
  }

  float2 skip = h2f2(*(const unsigned*)(qkvs + (size_t)v * NC2 + 384 + 2 * lane));
  float r = 1.0f / fmaxf(l, 1e-16f);
  if (d == 0) r = 0.0f;
  float* hd = h2 + (size_t)v * H1C + 2 * lane;
  *(float2*)hd = make_float2(skip.x + o0 * r, skip.y + o1 * r);
}

// ---------- batchnorm + activation ----------
__global__ __launch_bounds__(256) void k_bn_reduce(const float* __restrict__ h2,
                                                   float* __restrict__ bn, int Nrows){
  __shared__ float ls[256], lq[256];
  int c = threadIdx.x & 127;
  int half = threadIdx.x >> 7;
  float s = 0.0f, q = 0.0f;
  for (int r = blockIdx.x * 2 + half; r < Nrows; r += gridDim.x * 2){
    float v = h2[(size_t)r * H1C + c];
    s += v; q += v * v;
  }
  ls[threadIdx.x] = s; lq[threadIdx.x] = q;
  __syncthreads();
  if (half == 0){
    atomicAdd(&bn[c],        ls[c] + ls[c + 128]);
    atomicAdd(&bn[128 + c],  lq[c] + lq[c + 128]);
  }
}

__global__ void k_bn_final(float* __restrict__ bn, int Nrows){
  int c = threadIdx.x;
  if (c >= 128) return;
  float mu = bn[c] / (float)Nrows;
  float var = bn[128 + c] / (float)Nrows - mu * mu;
  bn[256 + c] = mu;
  bn[384 + c] = rsqrtf(var + 1e-5f);
}

__global__ void k_out(const float* __restrict__ h2, const float* __restrict__ bn,
                      const float* __restrict__ gamma, const float* __restrict__ beta,
                      float* __restrict__ out, int n){
  int idx = blockIdx.x * blockDim.x + threadIdx.x;
  if (idx >= n) return;
  int c = idx & 127;
  float v = (h2[idx] - bn[256 + c]) * bn[384 + c];
  float o = gamma[c] * v + beta[c];
  out[idx] = (o >= 0.0f) ? o : 0.01f * o;
}

// ---------- launcher ----------
extern "C" void kernel_launch(void* const* d_in, const int* in_sizes, int n_in,
                              void* d_out, int out_size, void* d_ws, size_t ws_size,
                              hipStream_t stream) {
  const float* x      = (const float*)d_in[0];
  const int*   ei     = (const int*)d_in[1];
  const int*   et     = (const int*)d_in[2];
  const float* W_rel  = (const float*)d_in[3];
  const float* W_root = (const float*)d_in[4];
  const float* b1     = (const float*)d_in[5];
  const float* Wq     = (const float*)d_in[6];
  const float* bq     = (const float*)d_in[7];
  const float* Wk     = (const float*)d_in[8];
  const float* bk     = (const float*)d_in[9];
  const float* Wv     = (const float*)d_in[10];
  const float* bv     = (const float*)d_in[11];
  const float* Wskip  = (const float*)d_in[12];
  const float* bskip  = (const float*)d_in[13];
  const float* gamma  = (const float*)d_in[14];
  const float* beta   = (const float*)d_in[15];
  float* out = (float*)d_out;

  const int N = NN, E = EE;
  char* ws = (char*)d_ws;
  size_t off = 0;
  auto alloc = [&](size_t bytes){ size_t r = off; off = (off + bytes + 255) & ~(size_t)255; return r; };

  size_t o_x16   = alloc((size_t)N * GD * 2);     // x fp16; REUSED as qkvs after gemm1
  size_t o_w1    = alloc((size_t)NC1 * GD * 2);
  size_t o_xw    = alloc((size_t)N * NC1 * 2);    // xW fp16; REUSED as h2 (f32) later
  // zero-region start (cnt..cursor contiguous)
  size_t o_cnt   = alloc((size_t)N * RR * 4);     // float counts per (node,rel)
  size_t o_deg   = alloc((size_t)N * 4);
  size_t o_cur   = alloc((size_t)N * 4);
  size_t o_zend  = off;
  size_t o_base  = alloc((size_t)N * 4);
  size_t o_bsum  = alloc((size_t)SCAN_BLK * 4);
  size_t o_boff  = alloc((size_t)SCAN_BLK * 4);
  size_t o_srt   = alloc((size_t)E * 4);
  size_t o_h16   = alloc((size_t)N * H1C * 2);
  size_t o_w2    = alloc((size_t)NC2 * H1C * 2);
  size_t o_b2    = alloc((size_t)NC2 * 4);
  size_t o_bn    = alloc((size_t)512 * 4);

  unsigned short* x16   = (unsigned short*)(ws + o_x16);
  unsigned short* qkvs  = (unsigned short*)(ws + o_x16);   // reuse
  unsigned short* wcatT = (unsigned short*)(ws + o_w1);
  unsigned short* xW    = (unsigned short*)(ws + o_xw);
  float*          h2    = (float*)(ws + o_xw);             // reuse
  float*          cnt   = (float*)(ws + o_cnt);
  int*            deg   = (int*)(ws + o_deg);
  int*            cursor= (int*)(ws + o_cur);
  int*            basea = (int*)(ws + o_base);
  int*            bsum  = (int*)(ws + o_bsum);
  int*            boff  = (int*)(ws + o_boff);
  unsigned*       srt   = (unsigned*)(ws + o_srt);
  unsigned short* h16   = (unsigned short*)(ws + o_h16);
  unsigned short* w2T   = (unsigned short*)(ws + o_w2);
  float*          bias2 = (float*)(ws + o_b2);
  float*          bn    = (float*)(ws + o_bn);

  const int TPB = 256;
  const int NBLK = (N + SCAN_BLK - 1) / SCAN_BLK;   // 196

  // ---- counting sort by dst (+ per-(dst,rel) counts) ----
  int nzero = (int)((o_zend - o_cnt) / 4);
  k_fill_u32<<<(nzero + TPB - 1) / TPB, TPB, 0, stream>>>((unsigned*)(ws + o_cnt), 0u, nzero);
  k_hist<<<(E + TPB - 1) / TPB, TPB, 0, stream>>>(ei, et, deg, cnt, E);
  k_scan_partial<<<NBLK, SCAN_BLK, 0, stream>>>(deg, bsum, N);
  k_scan_top<<<1, SCAN_BLK, 0, stream>>>(bsum, boff, NBLK);
  k_scan_final<<<NBLK, SCAN_BLK, 0, stream>>>(deg, boff, basea, N);
  k_scatter_perm<<<(E + TPB - 1) / TPB, TPB, 0, stream>>>(ei, et, basea, cursor, srt, E);

  // ---- GEMM1: xW = x @ [W_rel | W_root] ----
  k_cast_f16<<<((size_t)N * GD / 4 + TPB - 1) / TPB, TPB, 0, stream>>>(x, x16, N * GD);
  k_pack_w1<<<(NC1 * GD + TPB - 1) / TPB, TPB, 0, stream>>>(W_rel, W_root, wcatT);
  {
    dim3 grid((N + TILE - 1) / TILE, NC1 / TILE);
    k_gemm<<<grid, TPB, 0, stream>>>(x16, wcatT, xW, nullptr, N, NC1, GD);
  }

  // ---- RGCN segmented reduce -> h16 ----
  k_rgcn_seg<<<(N + 3) / 4, TPB, 0, stream>>>(basea, deg, srt, xW, cnt, b1, h16);

  // ---- GEMM2: qkvs = h @ [Wq|Wk|Wv|Wskip] + biases ----
  k_pack_w2<<<(NC2 * H1C + TPB - 1) / TPB, TPB, 0, stream>>>(Wq, Wk, Wv, Wskip, bq, bk, bv, bskip, w2T, bias2);
  {
    dim3 grid((N + TILE - 1) / TILE, NC2 / TILE);
    k_gemm<<<grid, TPB, 0, stream>>>(h16, w2T, qkvs, bias2, N, NC2, H1C);
  }

  // ---- fused attention -> h2 ----
  k_attn_seg<<<(N + 3) / 4, TPB, 0, stream>>>(basea, deg, srt, qkvs, h2);

  // ---- batchnorm + leaky relu ----
  k_fill_u32<<<2, 256, 0, stream>>>((unsigned*)bn, 0u, 512);
  k_bn_reduce<<<256, TPB, 0, stream>>>(h2, bn, N);
  k_bn_final<<<1, 128, 0, stream>>>(bn, N);
  k_out<<<((size_t)N * H1C + TPB - 1) / TPB, TPB, 0, stream>>>(h2, bn, gamma, beta, out, N * H1C);
}

// Round 4
// 636.846 us; speedup vs baseline: 9.7126x; 1.1813x over previous
//
#include <hip/hip_runtime.h>

typedef float f32x4 __attribute__((ext_vector_type(4)));
typedef _Float16 f16x8 __attribute__((ext_vector_type(8)));

#define NN 50000
#define EE 800000
#define GD 512
#define H1C 128
#define RR 8
#define NC1 1152   // 8*128 rel + 128 root
#define NC2 512    // q|k|v|skip
#define SCAN_BLK 256

// ---------- helpers ----------
__device__ __forceinline__ unsigned short f2h(float f){
  _Float16 h = (_Float16)f;
  unsigned short u; __builtin_memcpy(&u, &h, 2); return u;
}
__device__ __forceinline__ float h2f(unsigned short u){
  _Float16 h; __builtin_memcpy(&h, &u, 2); return (float)h;
}
__device__ __forceinline__ float wredsum(float v){
  #pragma unroll
  for (int off = 32; off >= 1; off >>= 1) v += __shfl_xor(v, off, 64);
  return v;
}
__device__ __forceinline__ float wredmax(float v){
  #pragma unroll
  for (int off = 32; off >= 1; off >>= 1) v = fmaxf(v, __shfl_xor(v, off, 64));
  return v;
}

// ---------- utility kernels ----------
__global__ void k_fill_u32(unsigned* p, unsigned v, int n){
  int i = blockIdx.x * blockDim.x + threadIdx.x;
  if (i < n) p[i] = v;
}

__global__ void k_pack_w1(const float* __restrict__ W_rel, const float* __restrict__ W_root,
                          unsigned short* __restrict__ wcatT){
  int idx = blockIdx.x * blockDim.x + threadIdx.x;
  if (idx >= NC1 * GD) return;
  int j = idx >> 9;
  int f = idx & 511;
  float v;
  if (j < 1024) v = W_rel[((size_t)(j >> 7) * GD + f) * H1C + (j & 127)];
  else          v = W_root[(size_t)f * H1C + (j - 1024)];
  wcatT[(size_t)j * GD + f] = f2h(v);
}

__global__ void k_pack_w2(const float* __restrict__ Wq, const float* __restrict__ Wk,
                          const float* __restrict__ Wv, const float* __restrict__ Ws,
                          const float* __restrict__ bq, const float* __restrict__ bk,
                          const float* __restrict__ bv, const float* __restrict__ bs,
                          unsigned short* __restrict__ w2T, float* __restrict__ bias2){
  int idx = blockIdx.x * blockDim.x + threadIdx.x;
  if (idx >= NC2 * H1C) return;
  int j = idx >> 7;
  int f = idx & 127;
  int m = j >> 7;
  int hc = j & 127;
  const float* W = (m == 0) ? Wq : (m == 1) ? Wk : (m == 2) ? Wv : Ws;
  w2T[(size_t)j * H1C + f] = f2h(W[(size_t)f * H1C + hc]);
  if (f == 0){
    const float* B = (m == 0) ? bq : (m == 1) ? bk : (m == 2) ? bv : bs;
    bias2[j] = B[hc];
  }
}

// ---------- counting sort by dst ----------
__global__ void k_hist(const int* __restrict__ ei, const int* __restrict__ et,
                       int* __restrict__ deg, float* __restrict__ cnt, int E){
  int e = blockIdx.x * blockDim.x + threadIdx.x;
  if (e >= E) return;
  int dst = ei[E + e];
  atomicAdd(&deg[dst], 1);
  atomicAdd(&cnt[(size_t)dst * RR + et[e]], 1.0f);
}

__global__ void k_scan_partial(const int* __restrict__ deg, int* __restrict__ bsum, int n){
  __shared__ int s[SCAN_BLK];
  int i = blockIdx.x * SCAN_BLK + threadIdx.x;
  s[threadIdx.x] = (i < n) ? deg[i] : 0;
  __syncthreads();
  for (int off = 128; off >= 1; off >>= 1){
    if (threadIdx.x < off) s[threadIdx.x] += s[threadIdx.x + off];
    __syncthreads();
  }
  if (threadIdx.x == 0) bsum[blockIdx.x] = s[0];
}

__global__ void k_scan_top(int* __restrict__ bsum, int* __restrict__ boff, int nb){
  __shared__ int s[SCAN_BLK];
  int t = threadIdx.x;
  int v = (t < nb) ? bsum[t] : 0;
  s[t] = v;
  __syncthreads();
  #pragma unroll
  for (int off = 1; off < SCAN_BLK; off <<= 1){
    int tv = (t >= off) ? s[t - off] : 0;
    __syncthreads();
    s[t] += tv;
    __syncthreads();
  }
  if (t < nb) boff[t] = s[t] - v;   // exclusive
}

__global__ void k_scan_final(const int* __restrict__ deg, const int* __restrict__ boff,
                             int* __restrict__ base, int n){
  __shared__ int s[SCAN_BLK];
  int i = blockIdx.x * SCAN_BLK + threadIdx.x;
  int t = threadIdx.x;
  int v = (i < n) ? deg[i] : 0;
  s[t] = v;
  __syncthreads();
  #pragma unroll
  for (int off = 1; off < SCAN_BLK; off <<= 1){
    int tv = (t >= off) ? s[t - off] : 0;
    __syncthreads();
    s[t] += tv;
    __syncthreads();
  }
  if (i < n) base[i] = s[t] - v + boff[blockIdx.x];   // exclusive global
}

// sortedSR[pos] = src | (rel<<16); sortedDst[pos] = dst (u16, N<65536)
__global__ void k_scatter_perm(const int* __restrict__ ei, const int* __restrict__ et,
                               const int* __restrict__ base, int* __restrict__ cursor,
                               unsigned* __restrict__ sortedSR,
                               unsigned short* __restrict__ sortedDst, int E){
  int e = blockIdx.x * blockDim.x + threadIdx.x;
  if (e >= E) return;
  int dst = ei[E + e];
  int pos = base[dst] + atomicAdd(&cursor[dst], 1);
  sortedSR[pos] = (unsigned)(ei[e] & 0xFFFF) | ((unsigned)et[e] << 16);
  sortedDst[pos] = (unsigned short)dst;
}

// ---------- MFMA GEMM common tile params ----------
#define TILE 128
#define BK 64
#define LDSS 72

// GEMM1: A is f32 (cast to f16 during staging). XCD-swizzled 1D grid:
// xcd = bid&7 owns rows [xcd*rowsPerXcd, ...) for all column blocks -> A-tile L2 reuse.
__global__ __launch_bounds__(256) void k_gemm_f32a(
    const float* __restrict__ A,
    const unsigned short* __restrict__ Bt,
    unsigned short* __restrict__ C,
    int M, int Nout, int K, int rowsPerXcd, int colBlocks)
{
  int bid = blockIdx.x;
  int xcd = bid & 7;
  int lin = bid >> 3;
  int rowb = xcd * rowsPerXcd + lin / colBlocks;
  int colb = lin % colBlocks;
  int row0 = rowb * TILE;
  if (row0 >= M) return;
  int col0 = colb * TILE;

  __shared__ unsigned short As[TILE][LDSS];
  __shared__ unsigned short Bs[TILE][LDSS];
  int tid = threadIdx.x;
  int wave = tid >> 6, lane = tid & 63;
  int wm = (wave >> 1) * 64, wn = (wave & 1) * 64;
  int l16 = lane & 15, quad = lane >> 4;

  f32x4 acc[4][4] = {};

  for (int k0 = 0; k0 < K; k0 += BK){
    __syncthreads();
    #pragma unroll
    for (int i = 0; i < 4; i++){
      int e = tid + i * 256;            // 0..1023
      int r = e >> 3, jc = e & 7;
      int gr = row0 + r; if (gr >= M) gr = M - 1;   // clamp; stores guarded
      const float* src = A + (size_t)gr * K + k0 + jc * 8;
      float4 a0 = *(const float4*)src;
      float4 a1 = *(const float4*)(src + 4);
      unsigned short v[8];
      v[0]=f2h(a0.x); v[1]=f2h(a0.y); v[2]=f2h(a0.z); v[3]=f2h(a0.w);
      v[4]=f2h(a1.x); v[5]=f2h(a1.y); v[6]=f2h(a1.z); v[7]=f2h(a1.w);
      *(uint4*)&As[r][jc * 8] = *(uint4*)v;
    }
    #pragma unroll
    for (int i = 0; i < 4; i++){
      int e = tid + i * 256;
      int r = e >> 3, jc = e & 7;
      int gc = col0 + r;
      *(uint4*)&Bs[r][jc * 8] = *(const uint4*)(Bt + (size_t)gc * K + k0 + jc * 8);
    }
    __syncthreads();
    #pragma unroll
    for (int ks = 0; ks < BK; ks += 32){
      f16x8 af[4], bfr[4];
      #pragma unroll
      for (int i = 0; i < 4; i++) af[i] = *(const f16x8*)&As[wm + i*16 + l16][ks + quad*8];
      #pragma unroll
      for (int j = 0; j < 4; j++) bfr[j] = *(const f16x8*)&Bs[wn + j*16 + l16][ks + quad*8];
      #pragma unroll
      for (int i = 0; i < 4; i++)
        #pragma unroll
        for (int j = 0; j < 4; j++)
          acc[i][j] = __builtin_amdgcn_mfma_f32_16x16x32_f16(af[i], bfr[j], acc[i][j], 0, 0, 0);
    }
  }

  #pragma unroll
  for (int i = 0; i < 4; i++){
    int rbase = row0 + wm + i*16 + quad*4;
    #pragma unroll
    for (int j = 0; j < 4; j++){
      int col = col0 + wn + j*16 + l16;
      #pragma unroll
      for (int rr = 0; rr < 4; rr++){
        int row = rbase + rr;
        if (row < M) C[(size_t)row * Nout + col] = f2h(acc[i][j][rr]);
      }
    }
  }
}

// GEMM2: A fp16, +bias, same swizzle
__global__ __launch_bounds__(256) void k_gemm_f16a(
    const unsigned short* __restrict__ A,
    const unsigned short* __restrict__ Bt,
    unsigned short* __restrict__ C,
    const float* __restrict__ bias,
    int M, int Nout, int K, int rowsPerXcd, int colBlocks)
{
  int bid = blockIdx.x;
  int xcd = bid & 7;
  int lin = bid >> 3;
  int rowb = xcd * rowsPerXcd + lin / colBlocks;
  int colb = lin % colBlocks;
  int row0 = rowb * TILE;
  if (row0 >= M) return;
  int col0 = colb * TILE;

  __shared__ unsigned short As[TILE][LDSS];
  __shared__ unsigned short Bs[TILE][LDSS];
  int tid = threadIdx.x;
  int wave = tid >> 6, lane = tid & 63;
  int wm = (wave >> 1) * 64, wn = (wave & 1) * 64;
  int l16 = lane & 15, quad = lane >> 4;

  f32x4 acc[4][4] = {};

  for (int k0 = 0; k0 < K; k0 += BK){
    __syncthreads();
    #pragma unroll
    for (int i = 0; i < 4; i++){
      int e = tid + i * 256;
      int r = e >> 3, jc = e & 7;
      int gr = row0 + r; if (gr >= M) gr = M - 1;
      *(uint4*)&As[r][jc * 8] = *(const uint4*)(A + (size_t)gr * K + k0 + jc * 8);
    }
    #pragma unroll
    for (int i = 0; i < 4; i++){
      int e = tid + i * 256;
      int r = e >> 3, jc = e & 7;
      int gc = col0 + r;
      *(uint4*)&Bs[r][jc * 8] = *(const uint4*)(Bt + (size_t)gc * K + k0 + jc * 8);
    }
    __syncthreads();
    #pragma unroll
    for (int ks = 0; ks < BK; ks += 32){
      f16x8 af[4], bfr[4];
      #pragma unroll
      for (int i = 0; i < 4; i++) af[i] = *(const f16x8*)&As[wm + i*16 + l16][ks + quad*8];
      #pragma unroll
      for (int j = 0; j < 4; j++) bfr[j] = *(const f16x8*)&Bs[wn + j*16 + l16][ks + quad*8];
      #pragma unroll
      for (int i = 0; i < 4; i++)
        #pragma unroll
        for (int j = 0; j < 4; j++)
          acc[i][j] = __builtin_amdgcn_mfma_f32_16x16x32_f16(af[i], bfr[j], acc[i][j], 0, 0, 0);
    }
  }

  #pragma unroll
  for (int i = 0; i < 4; i++){
    int rbase = row0 + wm + i*16 + quad*4;
    #pragma unroll
    for (int j = 0; j < 4; j++){
      int col = col0 + wn + j*16 + l16;
      float b = bias[col];
      #pragma unroll
      for (int rr = 0; rr < 4; rr++){
        int row = rbase + rr;
        if (row < M) C[(size_t)row * Nout + col] = f2h(acc[i][j][rr] + b);
      }
    }
  }
}

// ---------- RGCN segmented reduce: wave per node, gang-of-4 edges ----------
__global__ __launch_bounds__(256) void k_rgcn_seg(
    const int* __restrict__ base, const int* __restrict__ deg,
    const unsigned* __restrict__ srt,
    const unsigned short* __restrict__ xW, const float* __restrict__ cnt,
    const float* __restrict__ b1, unsigned short* __restrict__ h16)
{
  int v = blockIdx.x * 4 + (threadIdx.x >> 6);
  if (v >= NN) return;
  int lane = threadIdx.x & 63;
  int g = lane >> 4, l16 = lane & 15;
  int start = base[v], d = deg[v];
  const float* cv = cnt + (size_t)v * RR;

  float o[8] = {};
  for (int cb = 0; cb < d; cb += 64){
    int cc = min(64, d - cb);
    unsigned sr = (lane < cc) ? srt[start + cb + lane] : 0u;
    int nIter = (cc + 3) >> 2;
    for (int i = 0; i < nIter; i++){
      int idx = i * 4 + g;
      unsigned sri = (unsigned)__shfl((int)sr, idx, 64);
      int src = (int)(sri & 0xFFFFu);
      int rel = (int)(sri >> 16);
      float inv = (idx < cc) ? 1.0f / fmaxf(cv[rel], 1.0f) : 0.0f;
      uint4 u = *(const uint4*)(xW + (size_t)src * NC1 + rel * H1C + l16 * 8);
      const unsigned short* p = (const unsigned short*)&u;
      #pragma unroll
      for (int j = 0; j < 8; j++) o[j] += h2f(p[j]) * inv;
    }
  }
  #pragma unroll
  for (int j = 0; j < 8; j++){
    o[j] += __shfl_xor(o[j], 16, 64);
    o[j] += __shfl_xor(o[j], 32, 64);
  }
  if (g == 0){
    uint4 r = *(const uint4*)(xW + (size_t)v * NC1 + 1024 + l16 * 8);
    const unsigned short* p = (const unsigned short*)&r;
    unsigned short res[8];
    #pragma unroll
    for (int j = 0; j < 8; j++) res[j] = f2h(o[j] + h2f(p[j]) + b1[l16 * 8 + j]);
    *(uint4*)(h16 + (size_t)v * H1C + l16 * 8) = *(uint4*)res;
  }
}

// ---------- attention phase A: edge-parallel scores (sorted order) ----------
__global__ __launch_bounds__(256) void k_score2(
    const unsigned* __restrict__ srt, const unsigned short* __restrict__ sdst,
    const unsigned short* __restrict__ qkvs, float* __restrict__ score, int E)
{
  int t = blockIdx.x * 256 + threadIdx.x;
  int pos = t >> 4, j = t & 15;
  if (pos >= E) return;
  int src = (int)(srt[pos] & 0xFFFFu);
  int dst = (int)sdst[pos];
  uint4 qa = *(const uint4*)(qkvs + (size_t)dst * NC2 + j * 8);
  uint4 ka = *(const uint4*)(qkvs + (size_t)src * NC2 + 128 + j * 8);
  const unsigned short* qp = (const unsigned short*)&qa;
  const unsigned short* kp = (const unsigned short*)&ka;
  float s = 0.0f;
  #pragma unroll
  for (int i = 0; i < 8; i++) s += h2f(qp[i]) * h2f(kp[i]);
  #pragma unroll
  for (int off = 8; off >= 1; off >>= 1) s += __shfl_xor(s, off, 16);
  if (j == 0) score[pos] = s * 0.08838834764831845f;
}

// ---------- attention phase B: wave per node, chunk softmax + gang-of-4 V ----------
__global__ __launch_bounds__(256) void k_attn2(
    const int* __restrict__ base, const int* __restrict__ deg,
    const unsigned* __restrict__ srt, const float* __restrict__ score,
    const unsigned short* __restrict__ qkvs, float* __restrict__ h2)
{
  int v = blockIdx.x * 4 + (threadIdx.x >> 6);
  if (v >= NN) return;
  int lane = threadIdx.x & 63;
  int g = lane >> 4, l16 = lane & 15;
  int start = base[v], d = deg[v];

  float o[8] = {};
  float m = -INFINITY, l = 0.0f;

  for (int cb = 0; cb < d; cb += 64){
    int cc = min(64, d - cb);
    unsigned sr = (lane < cc) ? srt[start + cb + lane] : 0u;
    float s     = (lane < cc) ? score[start + cb + lane] : -INFINITY;
    float chm = wredmax(s);
    float newm = fmaxf(m, chm);
    float scale = expf(m - newm);      // 0 on first chunk
    float e = (lane < cc) ? expf(s - newm) : 0.0f;
    l = l * scale + wredsum(e);
    #pragma unroll
    for (int j = 0; j < 8; j++) o[j] *= scale;
    int nIter = (cc + 3) >> 2;
    for (int i = 0; i < nIter; i++){
      int idx = i * 4 + g;
      float a = __shfl(e, idx, 64);
      int sri = __shfl((int)sr, idx, 64);
      int src = sri & 0xFFFF;
      uint4 u = *(const uint4*)(qkvs + (size_t)src * NC2 + 256 + l16 * 8);
      const unsigned short* p = (const unsigned short*)&u;
      #pragma unroll
      for (int j = 0; j < 8; j++) o[j] += a * h2f(p[j]);
    }
    m = newm;
  }

  #pragma unroll
  for (int j = 0; j < 8; j++){
    o[j] += __shfl_xor(o[j], 16, 64);
    o[j] += __shfl_xor(o[j], 32, 64);
  }
  if (g == 0){
    float r = (d > 0) ? 1.0f / fmaxf(l, 1e-16f) : 0.0f;
    uint4 sk = *(const uint4*)(qkvs + (size_t)v * NC2 + 384 + l16 * 8);
    const unsigned short* p = (const unsigned short*)&sk;
    float* hd = h2 + (size_t)v * H1C + l16 * 8;
    float4 r0 = make_float4(h2f(p[0]) + o[0]*r, h2f(p[1]) + o[1]*r,
                            h2f(p[2]) + o[2]*r, h2f(p[3]) + o[3]*r);
    float4 r1 = make_float4(h2f(p[4]) + o[4]*r, h2f(p[5]) + o[5]*r,
                            h2f(p[6]) + o[6]*r, h2f(p[7]) + o[7]*r);
    *(float4*)hd = r0;
    *(float4*)(hd + 4) = r1;
  }
}

// ---------- batchnorm + activation ----------
__global__ __launch_bounds__(256) void k_bn_reduce(const float* __restrict__ h2,
                                                   float* __restrict__ bn, int Nrows){
  __shared__ float ls[256], lq[256];
  int c = threadIdx.x & 127;
  int half = threadIdx.x >> 7;
  float s = 0.0f, q = 0.0f;
  for (int r = blockIdx.x * 2 + half; r < Nrows; r += gridDim.x * 2){
    float v = h2[(size_t)r * H1C + c];
    s += v; q += v * v;
  }
  ls[threadIdx.x] = s; lq[threadIdx.x] = q;
  __syncthreads();
  if (half == 0){
    atomicAdd(&bn[c],        ls[c] + ls[c + 128]);
    atomicAdd(&bn[128 + c],  lq[c] + lq[c + 128]);
  }
}

__global__ void k_bn_final(float* __restrict__ bn, int Nrows){
  int c = threadIdx.x;
  if (c >= 128) return;
  float mu = bn[c] / (float)Nrows;
  float var = bn[128 + c] / (float)Nrows - mu * mu;
  bn[256 + c] = mu;
  bn[384 + c] = rsqrtf(var + 1e-5f);
}

__global__ void k_out(const float* __restrict__ h2, const float* __restrict__ bn,
                      const float* __restrict__ gamma, const float* __restrict__ beta,
                      float* __restrict__ out, int n){
  int idx = blockIdx.x * blockDim.x + threadIdx.x;
  if (idx >= n) return;
  int c = idx & 127;
  float v = (h2[idx] - bn[256 + c]) * bn[384 + c];
  float o = gamma[c] * v + beta[c];
  out[idx] = (o >= 0.0f) ? o : 0.01f * o;
}

// ---------- launcher ----------
extern "C" void kernel_launch(void* const* d_in, const int* in_sizes, int n_in,
                              void* d_out, int out_size, void* d_ws, size_t ws_size,
                              hipStream_t stream) {
  const float* x      = (const float*)d_in[0];
  const int*   ei     = (const int*)d_in[1];
  const int*   et     = (const int*)d_in[2];
  const float* W_rel  = (const float*)d_in[3];
  const float* W_root = (const float*)d_in[4];
  const float* b1     = (const float*)d_in[5];
  const float* Wq     = (const float*)d_in[6];
  const float* bq     = (const float*)d_in[7];
  const float* Wk     = (const float*)d_in[8];
  const float* bk     = (const float*)d_in[9];
  const float* Wv     = (const float*)d_in[10];
  const float* bv     = (const float*)d_in[11];
  const float* Wskip  = (const float*)d_in[12];
  const float* bskip  = (const float*)d_in[13];
  const float* gamma  = (const float*)d_in[14];
  const float* beta   = (const float*)d_in[15];
  float* out = (float*)d_out;

  const int N = NN, E = EE;
  char* ws = (char*)d_ws;
  size_t off = 0;
  auto alloc = [&](size_t bytes){ size_t r = off; off = (off + bytes + 255) & ~(size_t)255; return r; };

  size_t o_qkv   = alloc((size_t)N * NC2 * 2);    // qkvs fp16
  size_t o_w1    = alloc((size_t)NC1 * GD * 2);
  size_t o_xw    = alloc((size_t)N * NC1 * 2);    // xW fp16; REUSED as h2 (f32) after rgcn
  // zero-region (cnt..cursor contiguous)
  size_t o_cnt   = alloc((size_t)N * RR * 4);
  size_t o_deg   = alloc((size_t)N * 4);
  size_t o_cur   = alloc((size_t)N * 4);
  size_t o_zend  = off;
  size_t o_base  = alloc((size_t)N * 4);
  size_t o_bsum  = alloc((size_t)SCAN_BLK * 4);
  size_t o_boff  = alloc((size_t)SCAN_BLK * 4);
  size_t o_srt   = alloc((size_t)E * 4);
  size_t o_sd    = alloc((size_t)E * 2);
  size_t o_score = alloc((size_t)E * 4);
  size_t o_h16   = alloc((size_t)N * H1C * 2);
  size_t o_w2    = alloc((size_t)NC2 * H1C * 2);
  size_t o_b2    = alloc((size_t)NC2 * 4);
  size_t o_bn    = alloc((size_t)512 * 4);

  unsigned short* qkvs  = (unsigned short*)(ws + o_qkv);
  unsigned short* wcatT = (unsigned short*)(ws + o_w1);
  unsigned short* xW    = (unsigned short*)(ws + o_xw);
  float*          h2    = (float*)(ws + o_xw);             // reuse
  float*          cnt   = (float*)(ws + o_cnt);
  int*            deg   = (int*)(ws + o_deg);
  int*            cursor= (int*)(ws + o_cur);
  int*            basea = (int*)(ws + o_base);
  int*            bsum  = (int*)(ws + o_bsum);
  int*            boff  = (int*)(ws + o_boff);
  unsigned*       srt   = (unsigned*)(ws + o_srt);
  unsigned short* sdst  = (unsigned short*)(ws + o_sd);
  float*          score = (float*)(ws + o_score);
  unsigned short* h16   = (unsigned short*)(ws + o_h16);
  unsigned short* w2T   = (unsigned short*)(ws + o_w2);
  float*          bias2 = (float*)(ws + o_b2);
  float*          bn    = (float*)(ws + o_bn);

  const int TPB = 256;
  const int NBLK = (N + SCAN_BLK - 1) / SCAN_BLK;   // 196
  const int ROWB = (N + TILE - 1) / TILE;           // 391
  const int RPX  = (ROWB + 7) / 8;                  // 49 rows/XCD

  // ---- counting sort by dst (+ per-(dst,rel) counts) ----
  int nzero = (int)((o_zend - o_cnt) / 4);
  k_fill_u32<<<(nzero + TPB - 1) / TPB, TPB, 0, stream>>>((unsigned*)(ws + o_cnt), 0u, nzero);
  k_hist<<<(E + TPB - 1) / TPB, TPB, 0, stream>>>(ei, et, deg, cnt, E);
  k_scan_partial<<<NBLK, SCAN_BLK, 0, stream>>>(deg, bsum, N);
  k_scan_top<<<1, SCAN_BLK, 0, stream>>>(bsum, boff, NBLK);
  k_scan_final<<<NBLK, SCAN_BLK, 0, stream>>>(deg, boff, basea, N);
  k_scatter_perm<<<(E + TPB - 1) / TPB, TPB, 0, stream>>>(ei, et, basea, cursor, srt, sdst, E);

  // ---- GEMM1: xW = x @ [W_rel | W_root]  (inline f32->f16 A staging) ----
  k_pack_w1<<<(NC1 * GD + TPB - 1) / TPB, TPB, 0, stream>>>(W_rel, W_root, wcatT);
  k_gemm_f32a<<<8 * RPX * (NC1 / TILE), TPB, 0, stream>>>(x, wcatT, xW, N, NC1, GD, RPX, NC1 / TILE);

  // ---- RGCN segmented reduce -> h16 ----
  k_rgcn_seg<<<(N + 3) / 4, TPB, 0, stream>>>(basea, deg, srt, xW, cnt, b1, h16);

  // ---- GEMM2: qkvs = h @ [Wq|Wk|Wv|Wskip] + biases ----
  k_pack_w2<<<(NC2 * H1C + TPB - 1) / TPB, TPB, 0, stream>>>(Wq, Wk, Wv, Wskip, bq, bk, bv, bskip, w2T, bias2);
  k_gemm_f16a<<<8 * RPX * (NC2 / TILE), TPB, 0, stream>>>(h16, w2T, qkvs, bias2, N, NC2, H1C, RPX, NC2 / TILE);

  // ---- attention: parallel scores, then per-node softmax+V ----
  k_score2<<<(E * 16 + TPB - 1) / TPB, TPB, 0, stream>>>(srt, sdst, qkvs, score, E);
  k_attn2<<<(N + 3) / 4, TPB, 0, stream>>>(basea, deg, srt, score, qkvs, h2);

  // ---- batchnorm + leaky relu ----
  k_fill_u32<<<2, 256, 0, stream>>>((unsigned*)bn, 0u, 512);
  k_bn_reduce<<<256, TPB, 0, stream>>>(h2, bn, N);
  k_bn_final<<<1, 128, 0, stream>>>(bn, N);
  k_out<<<((size_t)N * H1C + TPB - 1) / TPB, TPB, 0, stream>>>(h2, bn, gamma, beta, out, N * H1C);
}

// Round 5
// 620.377 us; speedup vs baseline: 9.9704x; 1.0265x over previous
//
#include <hip/hip_runtime.h>

typedef float f32x4 __attribute__((ext_vector_type(4)));
typedef _Float16 f16x8 __attribute__((ext_vector_type(8)));

#define NN 50000
#define EE 800000
#define GD 512
#define H1C 128
#define RR 8
#define NC1 1152   // 8*128 rel + 128 root
#define NC2 512    // q|k|v|skip
#define SCAN_BLK 256

// ---------- helpers ----------
__device__ __forceinline__ unsigned short f2h(float f){
  _Float16 h = (_Float16)f;
  unsigned short u; __builtin_memcpy(&u, &h, 2); return u;
}
__device__ __forceinline__ float h2f(unsigned short u){
  _Float16 h; __builtin_memcpy(&h, &u, 2); return (float)h;
}
// async global->LDS, 16B per lane, LDS dest = wave-uniform base + lane*16
__device__ __forceinline__ void gload16(const void* g, void* l){
  __builtin_amdgcn_global_load_lds(
      (const __attribute__((address_space(1))) unsigned int*)g,
      (__attribute__((address_space(3))) unsigned int*)l, 16, 0, 0);
}

// ---------- utility kernels ----------
__global__ void k_fill_u32(unsigned* p, unsigned v, int n){
  int i = blockIdx.x * blockDim.x + threadIdx.x;
  if (i < n) p[i] = v;
}

__global__ void k_cast_f16(const float* __restrict__ in, unsigned short* __restrict__ out, int n){
  int i = (blockIdx.x * blockDim.x + threadIdx.x) * 4;
  if (i + 3 < n){
    float4 v = *(const float4*)(in + i);
    ushort4 o;
    o.x = f2h(v.x); o.y = f2h(v.y); o.z = f2h(v.z); o.w = f2h(v.w);
    *(ushort4*)(out + i) = o;
  }
}

__global__ void k_pack_w1(const float* __restrict__ W_rel, const float* __restrict__ W_root,
                          unsigned short* __restrict__ wcatT){
  int idx = blockIdx.x * blockDim.x + threadIdx.x;
  if (idx >= NC1 * GD) return;
  int j = idx >> 9;
  int f = idx & 511;
  float v;
  if (j < 1024) v = W_rel[((size_t)(j >> 7) * GD + f) * H1C + (j & 127)];
  else          v = W_root[(size_t)f * H1C + (j - 1024)];
  wcatT[(size_t)j * GD + f] = f2h(v);
}

__global__ void k_pack_w2(const float* __restrict__ Wq, const float* __restrict__ Wk,
                          const float* __restrict__ Wv, const float* __restrict__ Ws,
                          const float* __restrict__ bq, const float* __restrict__ bk,
                          const float* __restrict__ bv, const float* __restrict__ bs,
                          unsigned short* __restrict__ w2T, float* __restrict__ bias2){
  int idx = blockIdx.x * blockDim.x + threadIdx.x;
  if (idx >= NC2 * H1C) return;
  int j = idx >> 7;
  int f = idx & 127;
  int m = j >> 7;
  int hc = j & 127;
  const float* W = (m == 0) ? Wq : (m == 1) ? Wk : (m == 2) ? Wv : Ws;
  w2T[(size_t)j * H1C + f] = f2h(W[(size_t)f * H1C + hc]);
  if (f == 0){
    const float* B = (m == 0) ? bq : (m == 1) ? bk : (m == 2) ? bv : bs;
    bias2[j] = B[hc];
  }
}

// ---------- counting sort by dst ----------
__global__ void k_hist(const int* __restrict__ ei, const int* __restrict__ et,
                       int* __restrict__ deg, float* __restrict__ cnt, int E){
  int e = blockIdx.x * blockDim.x + threadIdx.x;
  if (e >= E) return;
  int dst = ei[E + e];
  atomicAdd(&deg[dst], 1);
  atomicAdd(&cnt[(size_t)dst * RR + et[e]], 1.0f);
}

__global__ void k_scan_partial(const int* __restrict__ deg, int* __restrict__ bsum, int n){
  __shared__ int s[SCAN_BLK];
  int i = blockIdx.x * SCAN_BLK + threadIdx.x;
  s[threadIdx.x] = (i < n) ? deg[i] : 0;
  __syncthreads();
  for (int off = 128; off >= 1; off >>= 1){
    if (threadIdx.x < off) s[threadIdx.x] += s[threadIdx.x + off];
    __syncthreads();
  }
  if (threadIdx.x == 0) bsum[blockIdx.x] = s[0];
}

__global__ void k_scan_top(int* __restrict__ bsum, int* __restrict__ boff, int nb){
  __shared__ int s[SCAN_BLK];
  int t = threadIdx.x;
  int v = (t < nb) ? bsum[t] : 0;
  s[t] = v;
  __syncthreads();
  #pragma unroll
  for (int off = 1; off < SCAN_BLK; off <<= 1){
    int tv = (t >= off) ? s[t - off] : 0;
    __syncthreads();
    s[t] += tv;
    __syncthreads();
  }
  if (t < nb) boff[t] = s[t] - v;   // exclusive
}

__global__ void k_scan_final(const int* __restrict__ deg, const int* __restrict__ boff,
                             int* __restrict__ base, int n){
  __shared__ int s[SCAN_BLK];
  int i = blockIdx.x * SCAN_BLK + threadIdx.x;
  int t = threadIdx.x;
  int v = (i < n) ? deg[i] : 0;
  s[t] = v;
  __syncthreads();
  #pragma unroll
  for (int off = 1; off < SCAN_BLK; off <<= 1){
    int tv = (t >= off) ? s[t - off] : 0;
    __syncthreads();
    s[t] += tv;
    __syncthreads();
  }
  if (i < n) base[i] = s[t] - v + boff[blockIdx.x];   // exclusive global
}

// sortedSR[pos] = src | (rel<<16)
__global__ void k_scatter_perm(const int* __restrict__ ei, const int* __restrict__ et,
                               const int* __restrict__ base, int* __restrict__ cursor,
                               unsigned* __restrict__ sortedSR, int E){
  int e = blockIdx.x * blockDim.x + threadIdx.x;
  if (e >= E) return;
  int dst = ei[E + e];
  int pos = base[dst] + atomicAdd(&cursor[dst], 1);
  sortedSR[pos] = (unsigned)(ei[e] & 0xFFFF) | ((unsigned)et[e] << 16);
}

// ---------- MFMA GEMM with global_load_lds + XOR-swizzled LDS ----------
// C[M][Nout] = A[M][K] @ Bt[Nout][K]^T (+bias). fp16 in/out.
// LDS storage: data (row, colblock cb) lives at As[row][(cb ^ (row&7))*8].
// Staging (global_load_lds, lane l -> base + l*16B): row = rbase + (l>>3),
// storage sc = l&7 => global cb = (l&7) ^ (l>>3)  (rbase multiple of 8).
#define TILE 128
#define BK 64

__global__ __launch_bounds__(256) void k_gemm(
    const unsigned short* __restrict__ A,
    const unsigned short* __restrict__ Bt,
    unsigned short* __restrict__ C,
    const float* __restrict__ bias,
    int M, int Nout, int K, int rowsPerXcd, int colBlocks)
{
  int bid = blockIdx.x;
  int xcd = bid & 7;
  int lin = bid >> 3;
  int rowb = xcd * rowsPerXcd + lin / colBlocks;
  int colb = lin % colBlocks;
  int row0 = rowb * TILE;
  if (row0 >= M) return;
  int col0 = colb * TILE;

  __shared__ unsigned short As[TILE][BK];
  __shared__ unsigned short Bs[TILE][BK];
  int tid = threadIdx.x;
  int wave = tid >> 6, lane = tid & 63;
  int wm = (wave >> 1) * 64, wn = (wave & 1) * 64;
  int l16 = lane & 15, quad = lane >> 4;

  // staging: lane -> (row offset, global colblock)
  int srow = lane >> 3;                       // 0..7
  int gcb  = ((lane & 7) ^ srow) * 8;         // global col (elems) within K-tile
  // fragment read: storage colblock = (quad + ks/8) ^ (l16&7)
  int xorr = l16 & 7;

  f32x4 acc[4][4] = {};

  for (int k0 = 0; k0 < K; k0 += BK){
    __syncthreads();
    #pragma unroll
    for (int i = 0; i < 4; i++){
      int rbase = (wave * 4 + i) * 8;         // 0..127 step 8
      int gr = row0 + rbase + srow; if (gr >= M) gr = M - 1;  // clamp; stores guarded
      gload16(A + (size_t)gr * K + k0 + gcb, &As[rbase][0]);
    }
    #pragma unroll
    for (int i = 0; i < 4; i++){
      int rbase = (wave * 4 + i) * 8;
      int gc = col0 + rbase + srow;           // Nout multiple of 128
      gload16(Bt + (size_t)gc * K + k0 + gcb, &Bs[rbase][0]);
    }
    __syncthreads();
    #pragma unroll
    for (int ks = 0; ks < BK; ks += 32){
      int scol = ((quad + (ks >> 3)) ^ xorr) * 8;
      f16x8 af[4], bfr[4];
      #pragma unroll
      for (int i = 0; i < 4; i++) af[i] = *(const f16x8*)&As[wm + i*16 + l16][scol];
      #pragma unroll
      for (int j = 0; j < 4; j++) bfr[j] = *(const f16x8*)&Bs[wn + j*16 + l16][scol];
      #pragma unroll
      for (int i = 0; i < 4; i++)
        #pragma unroll
        for (int j = 0; j < 4; j++)
          acc[i][j] = __builtin_amdgcn_mfma_f32_16x16x32_f16(af[i], bfr[j], acc[i][j], 0, 0, 0);
    }
  }

  // epilogue: C/D layout col=lane&15, row=quad*4+reg
  #pragma unroll
  for (int i = 0; i < 4; i++){
    int rbase = row0 + wm + i*16 + quad*4;
    #pragma unroll
    for (int j = 0; j < 4; j++){
      int col = col0 + wn + j*16 + l16;
      float b = bias ? bias[col] : 0.0f;
      #pragma unroll
      for (int rr = 0; rr < 4; rr++){
        int row = rbase + rr;
        if (row < M) C[(size_t)row * Nout + col] = f2h(acc[i][j][rr] + b);
      }
    }
  }
}

// ---------- RGCN segmented reduce: wave per node, gang-of-4 edges ----------
__global__ __launch_bounds__(256) void k_rgcn_seg(
    const int* __restrict__ base, const int* __restrict__ deg,
    const unsigned* __restrict__ srt,
    const unsigned short* __restrict__ xW, const float* __restrict__ cnt,
    const float* __restrict__ b1, unsigned short* __restrict__ h16)
{
  int v = blockIdx.x * 4 + (threadIdx.x >> 6);
  if (v >= NN) return;
  int lane = threadIdx.x & 63;
  int g = lane >> 4, l16 = lane & 15;
  int start = base[v], d = deg[v];
  const float* cv = cnt + (size_t)v * RR;

  float o[8] = {};
  for (int cb = 0; cb < d; cb += 4){
    int idx = cb + g;
    bool valid = idx < d;
    unsigned sri = valid ? srt[start + idx] : 0u;
    int src = (int)(sri & 0xFFFFu);
    int rel = (int)(sri >> 16);
    float inv = valid ? 1.0f / fmaxf(cv[rel], 1.0f) : 0.0f;
    uint4 u = *(const uint4*)(xW + (size_t)src * NC1 + rel * H1C + l16 * 8);
    const unsigned short* p = (const unsigned short*)&u;
    #pragma unroll
    for (int j = 0; j < 8; j++) o[j] += h2f(p[j]) * inv;
  }
  #pragma unroll
  for (int j = 0; j < 8; j++){
    o[j] += __shfl_xor(o[j], 16, 64);
    o[j] += __shfl_xor(o[j], 32, 64);
  }
  if (g == 0){
    uint4 r = *(const uint4*)(xW + (size_t)v * NC1 + 1024 + l16 * 8);
    const unsigned short* p = (const unsigned short*)&r;
    unsigned short res[8];
    #pragma unroll
    for (int j = 0; j < 8; j++) res[j] = f2h(o[j] + h2f(p[j]) + b1[l16 * 8 + j]);
    *(uint4*)(h16 + (size_t)v * H1C + l16 * 8) = *(uint4*)res;
  }
}

// ---------- fused attention: wave per node, gang-of-4 edges, online softmax ----------
__global__ __launch_bounds__(256) void k_attn3(
    const int* __restrict__ base, const int* __restrict__ deg,
    const unsigned* __restrict__ srt,
    const unsigned short* __restrict__ qkvs, float* __restrict__ h2)
{
  int v = blockIdx.x * 4 + (threadIdx.x >> 6);
  if (v >= NN) return;
  int lane = threadIdx.x & 63;
  int g = lane >> 4, l16 = lane & 15;
  int start = base[v], d = deg[v];
  const float sc = 0.08838834764831845f;   // 1/sqrt(128)

  // q chunk (8 ch) — identical across the 4 groups (broadcast load)
  float qf[8];
  {
    uint4 qa = *(const uint4*)(qkvs + (size_t)v * NC2 + l16 * 8);
    const unsigned short* p = (const unsigned short*)&qa;
    #pragma unroll
    for (int i = 0; i < 8; i++) qf[i] = h2f(p[i]);
  }

  float o[8] = {};
  float m = -INFINITY, l = 0.0f;

  for (int cb = 0; cb < d; cb += 4){
    int idx = cb + g;
    bool valid = idx < d;
    int src = valid ? (int)(srt[start + idx] & 0xFFFFu) : 0;

    // score for this group's edge
    float ss = 0.0f;
    {
      uint4 ka = *(const uint4*)(qkvs + (size_t)src * NC2 + 128 + l16 * 8);
      const unsigned short* p = (const unsigned short*)&ka;
      #pragma unroll
      for (int i = 0; i < 8; i++) ss += qf[i] * h2f(p[i]);
      #pragma unroll
      for (int off = 8; off >= 1; off >>= 1) ss += __shfl_xor(ss, off, 16);
    }
    float s = valid ? ss * sc : -INFINITY;

    // cross-group max + online softmax update
    float m4 = s;
    m4 = fmaxf(m4, __shfl_xor(m4, 16, 64));
    m4 = fmaxf(m4, __shfl_xor(m4, 32, 64));
    float newm = fmaxf(m, m4);
    float scale = __expf(m - newm);          // 0 on first iteration
    float e = valid ? __expf(s - newm) : 0.0f;
    float esum = e;
    esum += __shfl_xor(esum, 16, 64);
    esum += __shfl_xor(esum, 32, 64);
    l = l * scale + esum;

    // alpha-weighted V accumulate (per group)
    uint4 va = *(const uint4*)(qkvs + (size_t)src * NC2 + 256 + l16 * 8);
    const unsigned short* p = (const unsigned short*)&va;
    #pragma unroll
    for (int j = 0; j < 8; j++) o[j] = o[j] * scale + e * h2f(p[j]);
    m = newm;
  }

  // combine groups
  #pragma unroll
  for (int j = 0; j < 8; j++){
    o[j] += __shfl_xor(o[j], 16, 64);
    o[j] += __shfl_xor(o[j], 32, 64);
  }
  if (g == 0){
    float r = (d > 0) ? 1.0f / fmaxf(l, 1e-16f) : 0.0f;
    uint4 sk = *(const uint4*)(qkvs + (size_t)v * NC2 + 384 + l16 * 8);
    const unsigned short* p = (const unsigned short*)&sk;
    float* hd = h2 + (size_t)v * H1C + l16 * 8;
    float4 r0 = make_float4(h2f(p[0]) + o[0]*r, h2f(p[1]) + o[1]*r,
                            h2f(p[2]) + o[2]*r, h2f(p[3]) + o[3]*r);
    float4 r1 = make_float4(h2f(p[4]) + o[4]*r, h2f(p[5]) + o[5]*r,
                            h2f(p[6]) + o[6]*r, h2f(p[7]) + o[7]*r);
    *(float4*)hd = r0;
    *(float4*)(hd + 4) = r1;
  }
}

// ---------- batchnorm + activation ----------
__global__ __launch_bounds__(256) void k_bn_reduce(const float* __restrict__ h2,
                                                   float* __restrict__ bn, int Nrows){
  __shared__ float ls[256], lq[256];
  int c = threadIdx.x & 127;
  int half = threadIdx.x >> 7;
  float s = 0.0f, q = 0.0f;
  for (int r = blockIdx.x * 2 + half; r < Nrows; r += gridDim.x * 2){
    float v = h2[(size_t)r * H1C + c];
    s += v; q += v * v;
  }
  ls[threadIdx.x] = s; lq[threadIdx.x] = q;
  __syncthreads();
  if (half == 0){
    atomicAdd(&bn[c],        ls[c] + ls[c + 128]);
    atomicAdd(&bn[128 + c],  lq[c] + lq[c + 128]);
  }
}

__global__ void k_bn_final(float* __restrict__ bn, int Nrows){
  int c = threadIdx.x;
  if (c >= 128) return;
  float mu = bn[c] / (float)Nrows;
  float var = bn[128 + c] / (float)Nrows - mu * mu;
  bn[256 + c] = mu;
  bn[384 + c] = rsqrtf(var + 1e-5f);
}

__global__ void k_out(const float* __restrict__ h2, const float* __restrict__ bn,
                      const float* __restrict__ gamma, const float* __restrict__ beta,
                      float* __restrict__ out, int n){
  int idx = blockIdx.x * blockDim.x + threadIdx.x;
  if (idx >= n) return;
  int c = idx & 127;
  float v = (h2[idx] - bn[256 + c]) * bn[384 + c];
  float o = gamma[c] * v + beta[c];
  out[idx] = (o >= 0.0f) ? o : 0.01f * o;
}

// ---------- launcher ----------
extern "C" void kernel_launch(void* const* d_in, const int* in_sizes, int n_in,
                              void* d_out, int out_size, void* d_ws, size_t ws_size,
                              hipStream_t stream) {
  const float* x      = (const float*)d_in[0];
  const int*   ei     = (const int*)d_in[1];
  const int*   et     = (const int*)d_in[2];
  const float* W_rel  = (const float*)d_in[3];
  const float* W_root = (const float*)d_in[4];
  const float* b1     = (const float*)d_in[5];
  const float* Wq     = (const float*)d_in[6];
  const float* bq     = (const float*)d_in[7];
  const float* Wk     = (const float*)d_in[8];
  const float* bk     = (const float*)d_in[9];
  const float* Wv     = (const float*)d_in[10];
  const float* bv     = (const float*)d_in[11];
  const float* Wskip  = (const float*)d_in[12];
  const float* bskip  = (const float*)d_in[13];
  const float* gamma  = (const float*)d_in[14];
  const float* beta   = (const float*)d_in[15];
  float* out = (float*)d_out;

  const int N = NN, E = EE;
  char* ws = (char*)d_ws;
  size_t off = 0;
  auto alloc = [&](size_t bytes){ size_t r = off; off = (off + bytes + 255) & ~(size_t)255; return r; };

  size_t o_x16   = alloc((size_t)N * GD * 2);     // x fp16; REUSED as qkvs (same size)
  size_t o_w1    = alloc((size_t)NC1 * GD * 2);
  size_t o_xw    = alloc((size_t)N * NC1 * 2);    // xW fp16; REUSED as h2 (f32) after rgcn
  // zero-region (cnt..cursor contiguous)
  size_t o_cnt   = alloc((size_t)N * RR * 4);
  size_t o_deg   = alloc((size_t)N * 4);
  size_t o_cur   = alloc((size_t)N * 4);
  size_t o_zend  = off;
  size_t o_base  = alloc((size_t)N * 4);
  size_t o_bsum  = alloc((size_t)SCAN_BLK * 4);
  size_t o_boff  = alloc((size_t)SCAN_BLK * 4);
  size_t o_srt   = alloc((size_t)E * 4);
  size_t o_h16   = alloc((size_t)N * H1C * 2);
  size_t o_w2    = alloc((size_t)NC2 * H1C * 2);
  size_t o_b2    = alloc((size_t)NC2 * 4);
  size_t o_bn    = alloc((size_t)512 * 4);

  unsigned short* x16   = (unsigned short*)(ws + o_x16);
  unsigned short* qkvs  = (unsigned short*)(ws + o_x16);   // reuse
  unsigned short* wcatT = (unsigned short*)(ws + o_w1);
  unsigned short* xW    = (unsigned short*)(ws + o_xw);
  float*          h2    = (float*)(ws + o_xw);             // reuse
  float*          cnt   = (float*)(ws + o_cnt);
  int*            deg   = (int*)(ws + o_deg);
  int*            cursor= (int*)(ws + o_cur);
  int*            basea = (int*)(ws + o_base);
  int*            bsum  = (int*)(ws + o_bsum);
  int*            boff  = (int*)(ws + o_boff);
  unsigned*       srt   = (unsigned*)(ws + o_srt);
  unsigned short* h16   = (unsigned short*)(ws + o_h16);
  unsigned short* w2T   = (unsigned short*)(ws + o_w2);
  float*          bias2 = (float*)(ws + o_b2);
  float*          bn    = (float*)(ws + o_bn);

  const int TPB = 256;
  const int NBLK = (N + SCAN_BLK - 1) / SCAN_BLK;   // 196
  const int ROWB = (N + TILE - 1) / TILE;           // 391
  const int RPX  = (ROWB + 7) / 8;                  // 49 row-tiles/XCD

  // ---- counting sort by dst (+ per-(dst,rel) counts) ----
  int nzero = (int)((o_zend - o_cnt) / 4);
  k_fill_u32<<<(nzero + TPB - 1) / TPB, TPB, 0, stream>>>((unsigned*)(ws + o_cnt), 0u, nzero);
  k_hist<<<(E + TPB - 1) / TPB, TPB, 0, stream>>>(ei, et, deg, cnt, E);
  k_scan_partial<<<NBLK, SCAN_BLK, 0, stream>>>(deg, bsum, N);
  k_scan_top<<<1, SCAN_BLK, 0, stream>>>(bsum, boff, NBLK);
  k_scan_final<<<NBLK, SCAN_BLK, 0, stream>>>(deg, boff, basea, N);
  k_scatter_perm<<<(E + TPB - 1) / TPB, TPB, 0, stream>>>(ei, et, basea, cursor, srt, E);

  // ---- GEMM1: xW = x @ [W_rel | W_root] ----
  k_cast_f16<<<((size_t)N * GD / 4 + TPB - 1) / TPB, TPB, 0, stream>>>(x, x16, N * GD);
  k_pack_w1<<<(NC1 * GD + TPB - 1) / TPB, TPB, 0, stream>>>(W_rel, W_root, wcatT);
  k_gemm<<<8 * RPX * (NC1 / TILE), TPB, 0, stream>>>(x16, wcatT, xW, nullptr, N, NC1, GD, RPX, NC1 / TILE);

  // ---- RGCN segmented reduce -> h16 ----
  k_rgcn_seg<<<(N + 3) / 4, TPB, 0, stream>>>(basea, deg, srt, xW, cnt, b1, h16);

  // ---- GEMM2: qkvs = h @ [Wq|Wk|Wv|Wskip] + biases ----
  k_pack_w2<<<(NC2 * H1C + TPB - 1) / TPB, TPB, 0, stream>>>(Wq, Wk, Wv, Wskip, bq, bk, bv, bskip, w2T, bias2);
  k_gemm<<<8 * RPX * (NC2 / TILE), TPB, 0, stream>>>(h16, w2T, qkvs, bias2, N, NC2, H1C, RPX, NC2 / TILE);

  // ---- fused attention (scores + online softmax + V) -> h2 ----
  k_attn3<<<(N + 3) / 4, TPB, 0, stream>>>(basea, deg, srt, qkvs, h2);

  // ---- batchnorm + leaky relu ----
  k_fill_u32<<<2, 256, 0, stream>>>((unsigned*)bn, 0u, 512);
  k_bn_reduce<<<256, TPB, 0, stream>>>(h2, bn, N);
  k_bn_final<<<1, 128, 0, stream>>>(bn, N);
  k_out<<<((size_t)N * H1C + TPB - 1) / TPB, TPB, 0, stream>>>(h2, bn, gamma, beta, out, N * H1C);
}

// Round 6
// 569.918 us; speedup vs baseline: 10.8532x; 1.0885x over previous
//
#include <hip/hip_runtime.h>

typedef float f32x4 __attribute__((ext_vector_type(4)));
typedef _Float16 f16x8 __attribute__((ext_vector_type(8)));

#define NN 50000
#define EE 800000
#define GD 512
#define H1C 128
#define RR 8
#define NC1 1152   // 8*128 rel + 128 root
#define NC2 512    // q|k|v|skip
#define SCAN_BLK 256
#define NCAST (NN * GD / 4)   // f32->f16 cast items (4 elems each)

// ---------- helpers ----------
__device__ __forceinline__ unsigned short f2h(float f){
  _Float16 h = (_Float16)f;
  unsigned short u; __builtin_memcpy(&u, &h, 2); return u;
}
__device__ __forceinline__ float h2f(unsigned short u){
  _Float16 h; __builtin_memcpy(&h, &u, 2); return (float)h;
}
// async global->LDS, 16B per lane, LDS dest = wave-uniform base + lane*16
__device__ __forceinline__ void gload16(const void* g, void* l){
  __builtin_amdgcn_global_load_lds(
      (const __attribute__((address_space(1))) unsigned int*)g,
      (__attribute__((address_space(3))) unsigned int*)l, 16, 0, 0);
}

// ---------- fused prep: zero region + cast x + pack W1 + pack W2 ----------
__global__ void k_prep(unsigned* __restrict__ zp, int nzero,
                       const float* __restrict__ x, unsigned short* __restrict__ x16,
                       const float* __restrict__ W_rel, const float* __restrict__ W_root,
                       unsigned short* __restrict__ wcatT,
                       const float* __restrict__ Wq, const float* __restrict__ Wk,
                       const float* __restrict__ Wv, const float* __restrict__ Ws,
                       const float* __restrict__ bq, const float* __restrict__ bk,
                       const float* __restrict__ bv, const float* __restrict__ bs,
                       unsigned short* __restrict__ w2T, float* __restrict__ bias2){
  int i = blockIdx.x * 256 + threadIdx.x;
  if (i < nzero){ zp[i] = 0u; return; }
  i -= nzero;
  if (i < NCAST){
    int b = i * 4;
    float4 v = *(const float4*)(x + b);
    ushort4 o;
    o.x = f2h(v.x); o.y = f2h(v.y); o.z = f2h(v.z); o.w = f2h(v.w);
    *(ushort4*)(x16 + b) = o;
    return;
  }
  i -= NCAST;
  if (i < NC1 * GD){
    int j = i >> 9;
    int f = i & 511;
    float v;
    if (j < 1024) v = W_rel[((size_t)(j >> 7) * GD + f) * H1C + (j & 127)];
    else          v = W_root[(size_t)f * H1C + (j - 1024)];
    wcatT[(size_t)j * GD + f] = f2h(v);
    return;
  }
  i -= NC1 * GD;
  if (i < NC2 * H1C){
    int j = i >> 7;
    int f = i & 127;
    int m = j >> 7;
    int hc = j & 127;
    const float* W = (m == 0) ? Wq : (m == 1) ? Wk : (m == 2) ? Wv : Ws;
    w2T[(size_t)j * H1C + f] = f2h(W[(size_t)f * H1C + hc]);
    if (f == 0){
      const float* B = (m == 0) ? bq : (m == 1) ? bk : (m == 2) ? bv : bs;
      bias2[j] = B[hc];
    }
  }
}

// ---------- counting sort by dst ----------
__global__ void k_hist(const int* __restrict__ ei, const int* __restrict__ et,
                       float* __restrict__ cnt, int E){
  int e = blockIdx.x * blockDim.x + threadIdx.x;
  if (e >= E) return;
  atomicAdd(&cnt[(size_t)ei[E + e] * RR + et[e]], 1.0f);
}

// derive deg from cnt (sum of 8 per-rel counts), block partial sum -> bsum
__global__ void k_scan_partial(const float* __restrict__ cnt, int* __restrict__ deg,
                               int* __restrict__ bsum, int n){
  __shared__ int s[SCAN_BLK];
  int i = blockIdx.x * SCAN_BLK + threadIdx.x;
  int dv = 0;
  if (i < n){
    const float4* c = (const float4*)(cnt + (size_t)i * 8);
    float4 a = c[0], b = c[1];
    float fs = a.x + a.y + a.z + a.w + b.x + b.y + b.z + b.w;
    dv = (int)(fs + 0.5f);
    deg[i] = dv;
  }
  s[threadIdx.x] = dv;
  __syncthreads();
  for (int off = 128; off >= 1; off >>= 1){
    if (threadIdx.x < off) s[threadIdx.x] += s[threadIdx.x + off];
    __syncthreads();
  }
  if (threadIdx.x == 0) bsum[blockIdx.x] = s[0];
}

__global__ void k_scan_top(int* __restrict__ bsum, int* __restrict__ boff, int nb){
  __shared__ int s[SCAN_BLK];
  int t = threadIdx.x;
  int v = (t < nb) ? bsum[t] : 0;
  s[t] = v;
  __syncthreads();
  #pragma unroll
  for (int off = 1; off < SCAN_BLK; off <<= 1){
    int tv = (t >= off) ? s[t - off] : 0;
    __syncthreads();
    s[t] += tv;
    __syncthreads();
  }
  if (t < nb) boff[t] = s[t] - v;   // exclusive
}

__global__ void k_scan_final(const int* __restrict__ deg, const int* __restrict__ boff,
                             int* __restrict__ base, int n){
  __shared__ int s[SCAN_BLK];
  int i = blockIdx.x * SCAN_BLK + threadIdx.x;
  int t = threadIdx.x;
  int v = (i < n) ? deg[i] : 0;
  s[t] = v;
  __syncthreads();
  #pragma unroll
  for (int off = 1; off < SCAN_BLK; off <<= 1){
    int tv = (t >= off) ? s[t - off] : 0;
    __syncthreads();
    s[t] += tv;
    __syncthreads();
  }
  if (i < n) base[i] = s[t] - v + boff[blockIdx.x];   // exclusive global
}

// sortedSR[pos] = src | (rel<<16)
__global__ void k_scatter_perm(const int* __restrict__ ei, const int* __restrict__ et,
                               const int* __restrict__ base, int* __restrict__ cursor,
                               unsigned* __restrict__ sortedSR, int E){
  int e = blockIdx.x * blockDim.x + threadIdx.x;
  if (e >= E) return;
  int dst = ei[E + e];
  int pos = base[dst] + atomicAdd(&cursor[dst], 1);
  sortedSR[pos] = (unsigned)(ei[e] & 0xFFFF) | ((unsigned)et[e] << 16);
}

// ---------- MFMA GEMM with global_load_lds + XOR-swizzled LDS ----------
#define TILE 128
#define BK 64

__global__ __launch_bounds__(256) void k_gemm(
    const unsigned short* __restrict__ A,
    const unsigned short* __restrict__ Bt,
    unsigned short* __restrict__ C,
    const float* __restrict__ bias,
    int M, int Nout, int K, int rowsPerXcd, int colBlocks)
{
  int bid = blockIdx.x;
  int xcd = bid & 7;
  int lin = bid >> 3;
  int rowb = xcd * rowsPerXcd + lin / colBlocks;
  int colb = lin % colBlocks;
  int row0 = rowb * TILE;
  if (row0 >= M) return;
  int col0 = colb * TILE;

  __shared__ unsigned short As[TILE][BK];
  __shared__ unsigned short Bs[TILE][BK];
  int tid = threadIdx.x;
  int wave = tid >> 6, lane = tid & 63;
  int wm = (wave >> 1) * 64, wn = (wave & 1) * 64;
  int l16 = lane & 15, quad = lane >> 4;

  int srow = lane >> 3;                       // 0..7
  int gcb  = ((lane & 7) ^ srow) * 8;         // global col within K-tile
  int xorr = l16 & 7;

  f32x4 acc[4][4] = {};

  for (int k0 = 0; k0 < K; k0 += BK){
    __syncthreads();
    #pragma unroll
    for (int i = 0; i < 4; i++){
      int rbase = (wave * 4 + i) * 8;
      int gr = row0 + rbase + srow; if (gr >= M) gr = M - 1;  // clamp; stores guarded
      gload16(A + (size_t)gr * K + k0 + gcb, &As[rbase][0]);
    }
    #pragma unroll
    for (int i = 0; i < 4; i++){
      int rbase = (wave * 4 + i) * 8;
      int gc = col0 + rbase + srow;
      gload16(Bt + (size_t)gc * K + k0 + gcb, &Bs[rbase][0]);
    }
    __syncthreads();
    #pragma unroll
    for (int ks = 0; ks < BK; ks += 32){
      int scol = ((quad + (ks >> 3)) ^ xorr) * 8;
      f16x8 af[4], bfr[4];
      #pragma unroll
      for (int i = 0; i < 4; i++) af[i] = *(const f16x8*)&As[wm + i*16 + l16][scol];
      #pragma unroll
      for (int j = 0; j < 4; j++) bfr[j] = *(const f16x8*)&Bs[wn + j*16 + l16][scol];
      #pragma unroll
      for (int i = 0; i < 4; i++)
        #pragma unroll
        for (int j = 0; j < 4; j++)
          acc[i][j] = __builtin_amdgcn_mfma_f32_16x16x32_f16(af[i], bfr[j], acc[i][j], 0, 0, 0);
    }
  }

  #pragma unroll
  for (int i = 0; i < 4; i++){
    int rbase = row0 + wm + i*16 + quad*4;
    #pragma unroll
    for (int j = 0; j < 4; j++){
      int col = col0 + wn + j*16 + l16;
      float b = bias ? bias[col] : 0.0f;
      #pragma unroll
      for (int rr = 0; rr < 4; rr++){
        int row = rbase + rr;
        if (row < M) C[(size_t)row * Nout + col] = f2h(acc[i][j][rr] + b);
      }
    }
  }
}

// ---------- RGCN segmented reduce: wave/node, 16 edges per iter (4/group) ----------
__global__ __launch_bounds__(256) void k_rgcn_seg(
    const int* __restrict__ base, const int* __restrict__ deg,
    const unsigned* __restrict__ srt,
    const unsigned short* __restrict__ xW, const float* __restrict__ cnt,
    const float* __restrict__ b1, unsigned short* __restrict__ h16)
{
  int v = blockIdx.x * 4 + (threadIdx.x >> 6);
  if (v >= NN) return;
  int lane = threadIdx.x & 63;
  int g = lane >> 4, l16 = lane & 15;
  int start = base[v], d = deg[v];
  const float* cv = cnt + (size_t)v * RR;

  float o[8] = {};
  for (int cb = 0; cb < d; cb += 16){
    int srcs[4]; int rels[4]; float invs[4];
    #pragma unroll
    for (int t = 0; t < 4; t++){
      int idx = cb + 4 * t + g;
      bool valid = idx < d;
      unsigned sri = valid ? srt[start + idx] : 0u;
      srcs[t] = (int)(sri & 0xFFFFu);
      rels[t] = (int)(sri >> 16);
      invs[t] = valid ? 1.0f / fmaxf(cv[rels[t]], 1.0f) : 0.0f;
    }
    uint4 u[4];
    #pragma unroll
    for (int t = 0; t < 4; t++)
      u[t] = *(const uint4*)(xW + (size_t)srcs[t] * NC1 + rels[t] * H1C + l16 * 8);
    #pragma unroll
    for (int t = 0; t < 4; t++){
      const unsigned short* p = (const unsigned short*)&u[t];
      #pragma unroll
      for (int j = 0; j < 8; j++) o[j] += h2f(p[j]) * invs[t];
    }
  }
  #pragma unroll
  for (int j = 0; j < 8; j++){
    o[j] += __shfl_xor(o[j], 16, 64);
    o[j] += __shfl_xor(o[j], 32, 64);
  }
  if (g == 0){
    uint4 r = *(const uint4*)(xW + (size_t)v * NC1 + 1024 + l16 * 8);
    const unsigned short* p = (const unsigned short*)&r;
    unsigned short res[8];
    #pragma unroll
    for (int j = 0; j < 8; j++) res[j] = f2h(o[j] + h2f(p[j]) + b1[l16 * 8 + j]);
    *(uint4*)(h16 + (size_t)v * H1C + l16 * 8) = *(uint4*)res;
  }
}

// ---------- fused attention: wave/node, 16 edges per iter, online softmax ----------
__global__ __launch_bounds__(256) void k_attn3(
    const int* __restrict__ base, const int* __restrict__ deg,
    const unsigned* __restrict__ srt,
    const unsigned short* __restrict__ qkvs, float* __restrict__ h2)
{
  int v = blockIdx.x * 4 + (threadIdx.x >> 6);
  if (v >= NN) return;
  int lane = threadIdx.x & 63;
  int g = lane >> 4, l16 = lane & 15;
  int start = base[v], d = deg[v];
  const float sc = 0.08838834764831845f;   // 1/sqrt(128)

  float qf[8];
  {
    uint4 qa = *(const uint4*)(qkvs + (size_t)v * NC2 + l16 * 8);
    const unsigned short* p = (const unsigned short*)&qa;
    #pragma unroll
    for (int i = 0; i < 8; i++) qf[i] = h2f(p[i]);
  }

  float o[8] = {};
  float m = -INFINITY, l = 0.0f;

  for (int cb = 0; cb < d; cb += 16){
    int srcs[4]; bool val[4];
    #pragma unroll
    for (int t = 0; t < 4; t++){
      int idx = cb + 4 * t + g;
      val[t] = idx < d;
      srcs[t] = val[t] ? (int)(srt[start + idx] & 0xFFFFu) : 0;
    }
    uint4 ka[4], va[4];
    #pragma unroll
    for (int t = 0; t < 4; t++)
      ka[t] = *(const uint4*)(qkvs + (size_t)srcs[t] * NC2 + 128 + l16 * 8);
    #pragma unroll
    for (int t = 0; t < 4; t++)
      va[t] = *(const uint4*)(qkvs + (size_t)srcs[t] * NC2 + 256 + l16 * 8);

    float s[4];
    #pragma unroll
    for (int t = 0; t < 4; t++){
      const unsigned short* p = (const unsigned short*)&ka[t];
      float ss = 0.0f;
      #pragma unroll
      for (int i = 0; i < 8; i++) ss += qf[i] * h2f(p[i]);
      #pragma unroll
      for (int off = 8; off >= 1; off >>= 1) ss += __shfl_xor(ss, off, 16);
      s[t] = val[t] ? ss * sc : -INFINITY;
    }

    float m4 = fmaxf(fmaxf(s[0], s[1]), fmaxf(s[2], s[3]));
    m4 = fmaxf(m4, __shfl_xor(m4, 16, 64));
    m4 = fmaxf(m4, __shfl_xor(m4, 32, 64));
    float newm = fmaxf(m, m4);
    float scale = __expf(m - newm);          // 0 on first iteration
    float e[4], esum = 0.0f;
    #pragma unroll
    for (int t = 0; t < 4; t++){
      e[t] = val[t] ? __expf(s[t] - newm) : 0.0f;
      esum += e[t];
    }
    esum += __shfl_xor(esum, 16, 64);
    esum += __shfl_xor(esum, 32, 64);
    l = l * scale + esum;

    #pragma unroll
    for (int j = 0; j < 8; j++) o[j] *= scale;
    #pragma unroll
    for (int t = 0; t < 4; t++){
      const unsigned short* p = (const unsigned short*)&va[t];
      #pragma unroll
      for (int j = 0; j < 8; j++) o[j] += e[t] * h2f(p[j]);
    }
    m = newm;
  }

  #pragma unroll
  for (int j = 0; j < 8; j++){
    o[j] += __shfl_xor(o[j], 16, 64);
    o[j] += __shfl_xor(o[j], 32, 64);
  }
  if (g == 0){
    float r = (d > 0) ? 1.0f / fmaxf(l, 1e-16f) : 0.0f;
    uint4 sk = *(const uint4*)(qkvs + (size_t)v * NC2 + 384 + l16 * 8);
    const unsigned short* p = (const unsigned short*)&sk;
    float* hd = h2 + (size_t)v * H1C + l16 * 8;
    float4 r0 = make_float4(h2f(p[0]) + o[0]*r, h2f(p[1]) + o[1]*r,
                            h2f(p[2]) + o[2]*r, h2f(p[3]) + o[3]*r);
    float4 r1 = make_float4(h2f(p[4]) + o[4]*r, h2f(p[5]) + o[5]*r,
                            h2f(p[6]) + o[6]*r, h2f(p[7]) + o[7]*r);
    *(float4*)hd = r0;
    *(float4*)(hd + 4) = r1;
  }
}

// ---------- batchnorm + activation ----------
__global__ __launch_bounds__(256) void k_bn_reduce(const float* __restrict__ h2,
                                                   float* __restrict__ bn, int Nrows){
  __shared__ float ls[256], lq[256];
  int c = threadIdx.x & 127;
  int half = threadIdx.x >> 7;
  float s = 0.0f, q = 0.0f;
  for (int r = blockIdx.x * 2 + half; r < Nrows; r += gridDim.x * 2){
    float v = h2[(size_t)r * H1C + c];
    s += v; q += v * v;
  }
  ls[threadIdx.x] = s; lq[threadIdx.x] = q;
  __syncthreads();
  if (half == 0){
    atomicAdd(&bn[c],        ls[c] + ls[c + 128]);
    atomicAdd(&bn[128 + c],  lq[c] + lq[c + 128]);
  }
}

__global__ void k_out(const float* __restrict__ h2, const float* __restrict__ bn,
                      const float* __restrict__ gamma, const float* __restrict__ beta,
                      float* __restrict__ out, int n, float invN){
  int idx = blockIdx.x * blockDim.x + threadIdx.x;
  if (idx >= n) return;
  int c = idx & 127;
  float mu = bn[c] * invN;
  float var = bn[128 + c] * invN - mu * mu;
  float rs = rsqrtf(var + 1e-5f);
  float v = (h2[idx] - mu) * rs;
  float o = gamma[c] * v + beta[c];
  out[idx] = (o >= 0.0f) ? o : 0.01f * o;
}

// ---------- launcher ----------
extern "C" void kernel_launch(void* const* d_in, const int* in_sizes, int n_in,
                              void* d_out, int out_size, void* d_ws, size_t ws_size,
                              hipStream_t stream) {
  const float* x      = (const float*)d_in[0];
  const int*   ei     = (const int*)d_in[1];
  const int*   et     = (const int*)d_in[2];
  const float* W_rel  = (const float*)d_in[3];
  const float* W_root = (const float*)d_in[4];
  const float* b1     = (const float*)d_in[5];
  const float* Wq     = (const float*)d_in[6];
  const float* bq     = (const float*)d_in[7];
  const float* Wk     = (const float*)d_in[8];
  const float* bk     = (const float*)d_in[9];
  const float* Wv     = (const float*)d_in[10];
  const float* bv     = (const float*)d_in[11];
  const float* Wskip  = (const float*)d_in[12];
  const float* bskip  = (const float*)d_in[13];
  const float* gamma  = (const float*)d_in[14];
  const float* beta   = (const float*)d_in[15];
  float* out = (float*)d_out;

  const int N = NN, E = EE;
  char* ws = (char*)d_ws;
  size_t off = 0;
  auto alloc = [&](size_t bytes){ size_t r = off; off = (off + bytes + 255) & ~(size_t)255; return r; };

  size_t o_x16   = alloc((size_t)N * GD * 2);     // x fp16; REUSED as qkvs (same size)
  size_t o_w1    = alloc((size_t)NC1 * GD * 2);
  size_t o_xw    = alloc((size_t)N * NC1 * 2);    // xW fp16; REUSED as h2 (f32) after rgcn
  // zero-region (cnt..bn contiguous)
  size_t o_cnt   = alloc((size_t)N * RR * 4);
  size_t o_cur   = alloc((size_t)N * 4);
  size_t o_bn    = alloc((size_t)512 * 4);
  size_t o_zend  = off;
  size_t o_deg   = alloc((size_t)N * 4);
  size_t o_base  = alloc((size_t)N * 4);
  size_t o_bsum  = alloc((size_t)SCAN_BLK * 4);
  size_t o_boff  = alloc((size_t)SCAN_BLK * 4);
  size_t o_srt   = alloc((size_t)E * 4);
  size_t o_h16   = alloc((size_t)N * H1C * 2);
  size_t o_w2    = alloc((size_t)NC2 * H1C * 2);
  size_t o_b2    = alloc((size_t)NC2 * 4);

  unsigned short* x16   = (unsigned short*)(ws + o_x16);
  unsigned short* qkvs  = (unsigned short*)(ws + o_x16);   // reuse
  unsigned short* wcatT = (unsigned short*)(ws + o_w1);
  unsigned short* xW    = (unsigned short*)(ws + o_xw);
  float*          h2    = (float*)(ws + o_xw);             // reuse
  float*          cnt   = (float*)(ws + o_cnt);
  int*            cursor= (int*)(ws + o_cur);
  float*          bn    = (float*)(ws + o_bn);
  int*            deg   = (int*)(ws + o_deg);
  int*            basea = (int*)(ws + o_base);
  int*            bsum  = (int*)(ws + o_bsum);
  int*            boff  = (int*)(ws + o_boff);
  unsigned*       srt   = (unsigned*)(ws + o_srt);
  unsigned short* h16   = (unsigned short*)(ws + o_h16);
  unsigned short* w2T   = (unsigned short*)(ws + o_w2);
  float*          bias2 = (float*)(ws + o_b2);

  const int TPB = 256;
  const int NBLK = (N + SCAN_BLK - 1) / SCAN_BLK;   // 196
  const int ROWB = (N + TILE - 1) / TILE;           // 391
  const int RPX  = (ROWB + 7) / 8;                  // 49 row-tiles/XCD

  // ---- fused prep (zeros + cast x + pack weights) ----
  int nzero = (int)((o_zend - o_cnt) / 4);
  long prepN = (long)nzero + NCAST + NC1 * GD + NC2 * H1C;
  k_prep<<<(prepN + TPB - 1) / TPB, TPB, 0, stream>>>(
      (unsigned*)(ws + o_cnt), nzero, x, x16, W_rel, W_root, wcatT,
      Wq, Wk, Wv, Wskip, bq, bk, bv, bskip, w2T, bias2);

  // ---- counting sort by dst ----
  k_hist<<<(E + TPB - 1) / TPB, TPB, 0, stream>>>(ei, et, cnt, E);
  k_scan_partial<<<NBLK, SCAN_BLK, 0, stream>>>(cnt, deg, bsum, N);
  k_scan_top<<<1, SCAN_BLK, 0, stream>>>(bsum, boff, NBLK);
  k_scan_final<<<NBLK, SCAN_BLK, 0, stream>>>(deg, boff, basea, N);
  k_scatter_perm<<<(E + TPB - 1) / TPB, TPB, 0, stream>>>(ei, et, basea, cursor, srt, E);

  // ---- GEMM1: xW = x @ [W_rel | W_root] ----
  k_gemm<<<8 * RPX * (NC1 / TILE), TPB, 0, stream>>>(x16, wcatT, xW, nullptr, N, NC1, GD, RPX, NC1 / TILE);

  // ---- RGCN segmented reduce -> h16 ----
  k_rgcn_seg<<<(N + 3) / 4, TPB, 0, stream>>>(basea, deg, srt, xW, cnt, b1, h16);

  // ---- GEMM2: qkvs = h @ [Wq|Wk|Wv|Wskip] + biases ----
  k_gemm<<<8 * RPX * (NC2 / TILE), TPB, 0, stream>>>(h16, w2T, qkvs, bias2, N, NC2, H1C, RPX, NC2 / TILE);

  // ---- fused attention (scores + online softmax + V) -> h2 ----
  k_attn3<<<(N + 3) / 4, TPB, 0, stream>>>(basea, deg, srt, qkvs, h2);

  // ---- batchnorm + leaky relu ----
  k_bn_reduce<<<256, TPB, 0, stream>>>(h2, bn, N);
  k_out<<<((size_t)N * H1C + TPB - 1) / TPB, TPB, 0, stream>>>(h2, bn, gamma, beta, out, N * H1C, 1.0f / N);
}

// Round 7
// 563.360 us; speedup vs baseline: 10.9795x; 1.0116x over previous
//
#include <hip/hip_runtime.h>

typedef float f32x4 __attribute__((ext_vector_type(4)));
typedef _Float16 f16x8 __attribute__((ext_vector_type(8)));
typedef _Float16 f16x2 __attribute__((ext_vector_type(2)));

#define NN 50000
#define EE 800000
#define GD 512
#define H1C 128
#define RR 8
#define NC1 1152   // 8*128 rel + 128 root
#define NC2 512    // q|k|v|skip
#define NCAST (NN * GD / 4)   // f32->f16 cast items (4 elems each)

// ---------- helpers ----------
__device__ __forceinline__ unsigned short f2h(float f){
  _Float16 h = (_Float16)f;
  unsigned short u; __builtin_memcpy(&u, &h, 2); return u;
}
__device__ __forceinline__ float h2f(unsigned short u){
  _Float16 h; __builtin_memcpy(&h, &u, 2); return (float)h;
}
// async global->LDS, 16B per lane, LDS dest = wave-uniform base + lane*16
__device__ __forceinline__ void gload16(const void* g, void* l){
  __builtin_amdgcn_global_load_lds(
      (const __attribute__((address_space(1))) unsigned int*)g,
      (__attribute__((address_space(3))) unsigned int*)l, 16, 0, 0);
}
__device__ __forceinline__ float dot2(f16x2 a, f16x2 b, float c){
#if __has_builtin(__builtin_amdgcn_fdot2)
  return __builtin_amdgcn_fdot2(a, b, c, false);
#else
  return c + (float)a[0] * (float)b[0] + (float)a[1] * (float)b[1];
#endif
}

// ---------- fused prep: zero region + cast x + pack W1 + pack W2 ----------
__global__ void k_prep(unsigned* __restrict__ zp, int nzero,
                       const float* __restrict__ x, unsigned short* __restrict__ x16,
                       const float* __restrict__ W_rel, const float* __restrict__ W_root,
                       unsigned short* __restrict__ wcatT,
                       const float* __restrict__ Wq, const float* __restrict__ Wk,
                       const float* __restrict__ Wv, const float* __restrict__ Ws,
                       const float* __restrict__ bq, const float* __restrict__ bk,
                       const float* __restrict__ bv, const float* __restrict__ bs,
                       unsigned short* __restrict__ w2T, float* __restrict__ bias2){
  int i = blockIdx.x * 256 + threadIdx.x;
  if (i < nzero){ zp[i] = 0u; return; }
  i -= nzero;
  if (i < NCAST){
    int b = i * 4;
    float4 v = *(const float4*)(x + b);
    ushort4 o;
    o.x = f2h(v.x); o.y = f2h(v.y); o.z = f2h(v.z); o.w = f2h(v.w);
    *(ushort4*)(x16 + b) = o;
    return;
  }
  i -= NCAST;
  if (i < NC1 * GD){
    int j = i >> 9;
    int f = i & 511;
    float v;
    if (j < 1024) v = W_rel[((size_t)(j >> 7) * GD + f) * H1C + (j & 127)];
    else          v = W_root[(size_t)f * H1C + (j - 1024)];
    wcatT[(size_t)j * GD + f] = f2h(v);
    return;
  }
  i -= NC1 * GD;
  if (i < NC2 * H1C){
    int j = i >> 7;
    int f = i & 127;
    int m = j >> 7;
    int hc = j & 127;
    const float* W = (m == 0) ? Wq : (m == 1) ? Wk : (m == 2) ? Wv : Ws;
    w2T[(size_t)j * H1C + f] = f2h(W[(size_t)f * H1C + hc]);
    if (f == 0){
      const float* B = (m == 0) ? bq : (m == 1) ? bk : (m == 2) ? bv : bs;
      bias2[j] = B[hc];
    }
  }
}

// ---------- segment allocation (scan-free): base[v] = atomicAdd(total, deg) ----------
__global__ void k_alloc(const float* __restrict__ cnt, int* __restrict__ deg,
                        int* __restrict__ basea, int* __restrict__ cur,
                        unsigned* __restrict__ total, int n){
  int v = blockIdx.x * 256 + threadIdx.x;
  if (v >= n) return;
  const float4* c = (const float4*)(cnt + (size_t)v * 8);
  float4 a = c[0], b = c[1];
  int d = (int)(a.x + a.y + a.z + a.w + b.x + b.y + b.z + b.w + 0.5f);
  deg[v] = d;
  int base = (int)atomicAdd(total, (unsigned)d);
  basea[v] = base;
  cur[v] = base;
}

// sortedSR[pos] = src | (rel<<16)
__global__ void k_scatter_perm(const int* __restrict__ ei, const int* __restrict__ et,
                               int* __restrict__ cur, unsigned* __restrict__ sortedSR, int E){
  int e = blockIdx.x * blockDim.x + threadIdx.x;
  if (e >= E) return;
  int dst = ei[E + e];
  int pos = atomicAdd(&cur[dst], 1);
  sortedSR[pos] = (unsigned)(ei[e] & 0xFFFF) | ((unsigned)et[e] << 16);
}

// ---------- MFMA GEMM with global_load_lds + XOR-swizzled LDS ----------
// Extra blocks (bid >= gemmBlocks) do the edge histogram (independent work that
// fills CU gaps during the GEMM tail).
#define TILE 128
#define BK 64

__global__ __launch_bounds__(256) void k_gemm(
    const unsigned short* __restrict__ A,
    const unsigned short* __restrict__ Bt,
    unsigned short* __restrict__ C,
    const float* __restrict__ bias,
    int M, int Nout, int K, int rowsPerXcd, int colBlocks,
    int gemmBlocks, const int* __restrict__ ei, const int* __restrict__ et,
    float* __restrict__ cnt, int E)
{
  int bid = blockIdx.x;
  if (bid >= gemmBlocks){
    int e = (bid - gemmBlocks) * 256 + threadIdx.x;
    if (e < E) atomicAdd(&cnt[(size_t)ei[E + e] * RR + et[e]], 1.0f);
    return;
  }
  int xcd = bid & 7;
  int lin = bid >> 3;
  int rowb = xcd * rowsPerXcd + lin / colBlocks;
  int colb = lin % colBlocks;
  int row0 = rowb * TILE;
  if (row0 >= M) return;
  int col0 = colb * TILE;

  __shared__ unsigned short As[TILE][BK];
  __shared__ unsigned short Bs[TILE][BK];
  int tid = threadIdx.x;
  int wave = tid >> 6, lane = tid & 63;
  int wm = (wave >> 1) * 64, wn = (wave & 1) * 64;
  int l16 = lane & 15, quad = lane >> 4;

  int srow = lane >> 3;                       // 0..7
  int gcb  = ((lane & 7) ^ srow) * 8;         // global col within K-tile
  int xorr = l16 & 7;

  f32x4 acc[4][4] = {};

  for (int k0 = 0; k0 < K; k0 += BK){
    __syncthreads();
    #pragma unroll
    for (int i = 0; i < 4; i++){
      int rbase = (wave * 4 + i) * 8;
      int gr = row0 + rbase + srow; if (gr >= M) gr = M - 1;  // clamp; stores guarded
      gload16(A + (size_t)gr * K + k0 + gcb, &As[rbase][0]);
    }
    #pragma unroll
    for (int i = 0; i < 4; i++){
      int rbase = (wave * 4 + i) * 8;
      int gc = col0 + rbase + srow;
      gload16(Bt + (size_t)gc * K + k0 + gcb, &Bs[rbase][0]);
    }
    __syncthreads();
    #pragma unroll
    for (int ks = 0; ks < BK; ks += 32){
      int scol = ((quad + (ks >> 3)) ^ xorr) * 8;
      f16x8 af[4], bfr[4];
      #pragma unroll
      for (int i = 0; i < 4; i++) af[i] = *(const f16x8*)&As[wm + i*16 + l16][scol];
      #pragma unroll
      for (int j = 0; j < 4; j++) bfr[j] = *(const f16x8*)&Bs[wn + j*16 + l16][scol];
      #pragma unroll
      for (int i = 0; i < 4; i++)
        #pragma unroll
        for (int j = 0; j < 4; j++)
          acc[i][j] = __builtin_amdgcn_mfma_f32_16x16x32_f16(af[i], bfr[j], acc[i][j], 0, 0, 0);
    }
  }

  #pragma unroll
  for (int i = 0; i < 4; i++){
    int rbase = row0 + wm + i*16 + quad*4;
    #pragma unroll
    for (int j = 0; j < 4; j++){
      int col = col0 + wn + j*16 + l16;
      float b = bias ? bias[col] : 0.0f;
      #pragma unroll
      for (int rr = 0; rr < 4; rr++){
        int row = rbase + rr;
        if (row < M) C[(size_t)row * Nout + col] = f2h(acc[i][j][rr] + b);
      }
    }
  }
}

// ---------- RGCN segmented reduce: wave/node, 16 edges per iter (4/group) ----------
__global__ __launch_bounds__(256) void k_rgcn_seg(
    const int* __restrict__ base, const int* __restrict__ deg,
    const unsigned* __restrict__ srt,
    const unsigned short* __restrict__ xW, const float* __restrict__ cnt,
    const float* __restrict__ b1, unsigned short* __restrict__ h16)
{
  int v = blockIdx.x * 4 + (threadIdx.x >> 6);
  if (v >= NN) return;
  int lane = threadIdx.x & 63;
  int g = lane >> 4, l16 = lane & 15;
  int start = base[v], d = deg[v];
  const float* cv = cnt + (size_t)v * RR;

  float o[8] = {};
  for (int cb = 0; cb < d; cb += 16){
    int srcs[4]; int rels[4]; float invs[4];
    #pragma unroll
    for (int t = 0; t < 4; t++){
      int idx = cb + 4 * t + g;
      bool valid = idx < d;
      unsigned sri = valid ? srt[start + idx] : 0u;
      srcs[t] = (int)(sri & 0xFFFFu);
      rels[t] = (int)(sri >> 16);
      invs[t] = valid ? 1.0f / fmaxf(cv[rels[t]], 1.0f) : 0.0f;
    }
    uint4 u[4];
    #pragma unroll
    for (int t = 0; t < 4; t++)
      u[t] = *(const uint4*)(xW + (size_t)srcs[t] * NC1 + rels[t] * H1C + l16 * 8);
    #pragma unroll
    for (int t = 0; t < 4; t++){
      const unsigned short* p = (const unsigned short*)&u[t];
      #pragma unroll
      for (int j = 0; j < 8; j++) o[j] += h2f(p[j]) * invs[t];
    }
  }
  #pragma unroll
  for (int j = 0; j < 8; j++){
    o[j] += __shfl_xor(o[j], 16, 64);
    o[j] += __shfl_xor(o[j], 32, 64);
  }
  if (g == 0){
    uint4 r = *(const uint4*)(xW + (size_t)v * NC1 + 1024 + l16 * 8);
    const unsigned short* p = (const unsigned short*)&r;
    unsigned short res[8];
    #pragma unroll
    for (int j = 0; j < 8; j++) res[j] = f2h(o[j] + h2f(p[j]) + b1[l16 * 8 + j]);
    *(uint4*)(h16 + (size_t)v * H1C + l16 * 8) = *(uint4*)res;
  }
}

// ---------- fused attention: wave/node, 16 edges per iter, online softmax ----------
__global__ __launch_bounds__(256) void k_attn3(
    const int* __restrict__ base, const int* __restrict__ deg,
    const unsigned* __restrict__ srt,
    const unsigned short* __restrict__ qkvs, float* __restrict__ h2)
{
  int v = blockIdx.x * 4 + (threadIdx.x >> 6);
  if (v >= NN) return;
  int lane = threadIdx.x & 63;
  int g = lane >> 4, l16 = lane & 15;
  int start = base[v], d = deg[v];
  const float sc = 0.08838834764831845f;   // 1/sqrt(128)

  uint4 qa = *(const uint4*)(qkvs + (size_t)v * NC2 + l16 * 8);
  const f16x2* qh = (const f16x2*)&qa;     // 4 packed f16 pairs

  float o[8] = {};
  float m = -INFINITY, l = 0.0f;

  for (int cb = 0; cb < d; cb += 16){
    int srcs[4]; bool val[4];
    #pragma unroll
    for (int t = 0; t < 4; t++){
      int idx = cb + 4 * t + g;
      val[t] = idx < d;
      srcs[t] = val[t] ? (int)(srt[start + idx] & 0xFFFFu) : 0;
    }
    uint4 ka[4], va[4];
    #pragma unroll
    for (int t = 0; t < 4; t++)
      ka[t] = *(const uint4*)(qkvs + (size_t)srcs[t] * NC2 + 128 + l16 * 8);
    #pragma unroll
    for (int t = 0; t < 4; t++)
      va[t] = *(const uint4*)(qkvs + (size_t)srcs[t] * NC2 + 256 + l16 * 8);

    float s[4];
    #pragma unroll
    for (int t = 0; t < 4; t++){
      const f16x2* kh = (const f16x2*)&ka[t];
      float ss = 0.0f;
      #pragma unroll
      for (int i = 0; i < 4; i++) ss = dot2(qh[i], kh[i], ss);
      #pragma unroll
      for (int off = 8; off >= 1; off >>= 1) ss += __shfl_xor(ss, off, 16);
      s[t] = val[t] ? ss * sc : -INFINITY;
    }

    float m4 = fmaxf(fmaxf(s[0], s[1]), fmaxf(s[2], s[3]));
    m4 = fmaxf(m4, __shfl_xor(m4, 16, 64));
    m4 = fmaxf(m4, __shfl_xor(m4, 32, 64));
    float newm = fmaxf(m, m4);
    float scale = __expf(m - newm);          // 0 on first iteration
    float e[4], esum = 0.0f;
    #pragma unroll
    for (int t = 0; t < 4; t++){
      e[t] = val[t] ? __expf(s[t] - newm) : 0.0f;
      esum += e[t];
    }
    esum += __shfl_xor(esum, 16, 64);
    esum += __shfl_xor(esum, 32, 64);
    l = l * scale + esum;

    #pragma unroll
    for (int j = 0; j < 8; j++) o[j] *= scale;
    #pragma unroll
    for (int t = 0; t < 4; t++){
      const unsigned short* p = (const unsigned short*)&va[t];
      #pragma unroll
      for (int j = 0; j < 8; j++) o[j] += e[t] * h2f(p[j]);
    }
    m = newm;
  }

  #pragma unroll
  for (int j = 0; j < 8; j++){
    o[j] += __shfl_xor(o[j], 16, 64);
    o[j] += __shfl_xor(o[j], 32, 64);
  }
  if (g == 0){
    float r = (d > 0) ? 1.0f / fmaxf(l, 1e-16f) : 0.0f;
    uint4 sk = *(const uint4*)(qkvs + (size_t)v * NC2 + 384 + l16 * 8);
    const unsigned short* p = (const unsigned short*)&sk;
    float* hd = h2 + (size_t)v * H1C + l16 * 8;
    float4 r0 = make_float4(h2f(p[0]) + o[0]*r, h2f(p[1]) + o[1]*r,
                            h2f(p[2]) + o[2]*r, h2f(p[3]) + o[3]*r);
    float4 r1 = make_float4(h2f(p[4]) + o[4]*r, h2f(p[5]) + o[5]*r,
                            h2f(p[6]) + o[6]*r, h2f(p[7]) + o[7]*r);
    *(float4*)hd = r0;
    *(float4*)(hd + 4) = r1;
  }
}

// ---------- batchnorm + activation ----------
__global__ __launch_bounds__(256) void k_bn_reduce(const float* __restrict__ h2,
                                                   float* __restrict__ bn, int Nrows){
  __shared__ float ls[256], lq[256];
  int c = threadIdx.x & 127;
  int half = threadIdx.x >> 7;
  float s = 0.0f, q = 0.0f;
  for (int r = blockIdx.x * 2 + half; r < Nrows; r += gridDim.x * 2){
    float v = h2[(size_t)r * H1C + c];
    s += v; q += v * v;
  }
  ls[threadIdx.x] = s; lq[threadIdx.x] = q;
  __syncthreads();
  if (half == 0){
    atomicAdd(&bn[c],        ls[c] + ls[c + 128]);
    atomicAdd(&bn[128 + c],  lq[c] + lq[c + 128]);
  }
}

__global__ void k_out(const float* __restrict__ h2, const float* __restrict__ bn,
                      const float* __restrict__ gamma, const float* __restrict__ beta,
                      float* __restrict__ out, int n, float invN){
  int idx = blockIdx.x * blockDim.x + threadIdx.x;
  if (idx >= n) return;
  int c = idx & 127;
  float mu = bn[c] * invN;
  float var = bn[128 + c] * invN - mu * mu;
  float rs = rsqrtf(var + 1e-5f);
  float v = (h2[idx] - mu) * rs;
  float o = gamma[c] * v + beta[c];
  out[idx] = (o >= 0.0f) ? o : 0.01f * o;
}

// ---------- launcher ----------
extern "C" void kernel_launch(void* const* d_in, const int* in_sizes, int n_in,
                              void* d_out, int out_size, void* d_ws, size_t ws_size,
                              hipStream_t stream) {
  const float* x      = (const float*)d_in[0];
  const int*   ei     = (const int*)d_in[1];
  const int*   et     = (const int*)d_in[2];
  const float* W_rel  = (const float*)d_in[3];
  const float* W_root = (const float*)d_in[4];
  const float* b1     = (const float*)d_in[5];
  const float* Wq     = (const float*)d_in[6];
  const float* bq     = (const float*)d_in[7];
  const float* Wk     = (const float*)d_in[8];
  const float* bk     = (const float*)d_in[9];
  const float* Wv     = (const float*)d_in[10];
  const float* bv     = (const float*)d_in[11];
  const float* Wskip  = (const float*)d_in[12];
  const float* bskip  = (const float*)d_in[13];
  const float* gamma  = (const float*)d_in[14];
  const float* beta   = (const float*)d_in[15];
  float* out = (float*)d_out;

  const int N = NN, E = EE;
  char* ws = (char*)d_ws;
  size_t off = 0;
  auto alloc = [&](size_t bytes){ size_t r = off; off = (off + bytes + 255) & ~(size_t)255; return r; };

  size_t o_x16   = alloc((size_t)N * GD * 2);     // x fp16; REUSED as qkvs (same size)
  size_t o_w1    = alloc((size_t)NC1 * GD * 2);
  size_t o_xw    = alloc((size_t)N * NC1 * 2);    // xW fp16; REUSED as h2 (f32) after rgcn
  // zero-region (cnt..total contiguous)
  size_t o_cnt   = alloc((size_t)N * RR * 4);
  size_t o_bn    = alloc((size_t)512 * 4);
  size_t o_tot   = alloc((size_t)64 * 4);
  size_t o_zend  = off;
  size_t o_deg   = alloc((size_t)N * 4);
  size_t o_base  = alloc((size_t)N * 4);
  size_t o_cur   = alloc((size_t)N * 4);
  size_t o_srt   = alloc((size_t)E * 4);
  size_t o_h16   = alloc((size_t)N * H1C * 2);
  size_t o_w2    = alloc((size_t)NC2 * H1C * 2);
  size_t o_b2    = alloc((size_t)NC2 * 4);

  unsigned short* x16   = (unsigned short*)(ws + o_x16);
  unsigned short* qkvs  = (unsigned short*)(ws + o_x16);   // reuse
  unsigned short* wcatT = (unsigned short*)(ws + o_w1);
  unsigned short* xW    = (unsigned short*)(ws + o_xw);
  float*          h2    = (float*)(ws + o_xw);             // reuse
  float*          cnt   = (float*)(ws + o_cnt);
  float*          bn    = (float*)(ws + o_bn);
  unsigned*       total = (unsigned*)(ws + o_tot);
  int*            deg   = (int*)(ws + o_deg);
  int*            basea = (int*)(ws + o_base);
  int*            cur   = (int*)(ws + o_cur);
  unsigned*       srt   = (unsigned*)(ws + o_srt);
  unsigned short* h16   = (unsigned short*)(ws + o_h16);
  unsigned short* w2T   = (unsigned short*)(ws + o_w2);
  float*          bias2 = (float*)(ws + o_b2);

  const int TPB = 256;
  const int ROWB = (N + TILE - 1) / TILE;           // 391
  const int RPX  = (ROWB + 7) / 8;                  // 49 row-tiles/XCD
  const int HISTB = (E + TPB - 1) / TPB;            // 3125

  // ---- fused prep (zeros + cast x + pack weights) ----
  int nzero = (int)((o_zend - o_cnt) / 4);
  long prepN = (long)nzero + NCAST + NC1 * GD + NC2 * H1C;
  k_prep<<<(prepN + TPB - 1) / TPB, TPB, 0, stream>>>(
      (unsigned*)(ws + o_cnt), nzero, x, x16, W_rel, W_root, wcatT,
      Wq, Wk, Wv, Wskip, bq, bk, bv, bskip, w2T, bias2);

  // ---- GEMM1 (xW = x @ [W_rel|W_root]) + edge histogram in one launch ----
  {
    int gemmB = 8 * RPX * (NC1 / TILE);
    k_gemm<<<gemmB + HISTB, TPB, 0, stream>>>(x16, wcatT, xW, nullptr,
        N, NC1, GD, RPX, NC1 / TILE, gemmB, ei, et, cnt, E);
  }

  // ---- segment alloc + permutation (counting sort, scan-free) ----
  k_alloc<<<(N + TPB - 1) / TPB, TPB, 0, stream>>>(cnt, deg, basea, cur, total, N);
  k_scatter_perm<<<HISTB, TPB, 0, stream>>>(ei, et, cur, srt, E);

  // ---- RGCN segmented reduce -> h16 ----
  k_rgcn_seg<<<(N + 3) / 4, TPB, 0, stream>>>(basea, deg, srt, xW, cnt, b1, h16);

  // ---- GEMM2: qkvs = h @ [Wq|Wk|Wv|Wskip] + biases ----
  {
    int gemmB = 8 * RPX * (NC2 / TILE);
    k_gemm<<<gemmB, TPB, 0, stream>>>(h16, w2T, qkvs, bias2,
        N, NC2, H1C, RPX, NC2 / TILE, gemmB, nullptr, nullptr, cnt, 0);
  }

  // ---- fused attention (scores + online softmax + V) -> h2 ----
  k_attn3<<<(N + 3) / 4, TPB, 0, stream>>>(basea, deg, srt, qkvs, h2);

  // ---- batchnorm + leaky relu ----
  k_bn_reduce<<<256, TPB, 0, stream>>>(h2, bn, N);
  k_out<<<((size_t)N * H1C + TPB - 1) / TPB, TPB, 0, stream>>>(h2, bn, gamma, beta, out, N * H1C, 1.0f / N);
}